// Round 8
// baseline (507.079 us; speedup 1.0000x reference)
//
#include <hip/hip_runtime.h>

#define NU 100000
#define NI 50000
#define NN 150000   // NU + NI
#define D  64
#define CAP 47      // bucket capacity per dst; E[max in-degree] ~44 for Poisson(21.3)
#define OVF_MAX 4096

// binning params
#define BINSHIFT 9
#define BINW 512                 // dsts per bin
#define NBINS 293                // ceil(150000/512)
#define BINCAP 11448             // per-bin record cap, multiple of 8
#define STAGE_CAP 20             // LDS stage slots per bin
#define EPT 4                    // edges per thread per batch
#define SPILL_CAP 262144

typedef unsigned int uint;
typedef unsigned short ushort;

// ---------------- helpers ----------------
__device__ __forceinline__ float half_reduce_add(float v) {  // reduce within 32-lane half
    #pragma unroll
    for (int m = 16; m >= 1; m >>= 1) v += __shfl_xor(v, m, 64);
    return v;
}
__device__ __forceinline__ ushort f2bf(float f) {   // round-to-nearest-even
    union { float f; uint i; } c; c.f = f;
    uint r = c.i + 0x7FFF + ((c.i >> 16) & 1);
    return (ushort)(r >> 16);
}
__device__ __forceinline__ float lane_bcast(float v, int l) {
    return __int_as_float(__builtin_amdgcn_readlane(__float_as_int(v), l));
}
__device__ __forceinline__ uint q14(float w) {
    int q = (int)(w * 16384.0f);
    q = (q < 0) ? 0 : (q > 16383 ? 16383 : q);
    return (uint)q;
}
__device__ __forceinline__ void spill_one(int d, uint s, float w,
        uint2* __restrict__ spill, int* __restrict__ spillcnt) {
    int si = atomicAdd(spillcnt, 1);
    if (si < SPILL_CAP) spill[si] = make_uint2(s | (q14(w) << 18), (uint)d);
}

// ---------------- pass 1: LDS-staged binning, line-coalesced flushes ----------
// bin record: word0 = src18 | dlocal9<<18 ; word1 = float weight bits
__global__ __launch_bounds__(256) void k_bin(
        const int* __restrict__ src, const int* __restrict__ dst,
        const float* __restrict__ ew, int* __restrict__ bincur,
        uint2* __restrict__ binbuf, uint2* __restrict__ spill,
        int* __restrict__ spillcnt, int E) {
    __shared__ uint2 stage[NBINS][STAGE_CAP];   // ~47 KB -> 3 blocks/CU
    __shared__ int scnt[NBINS];
    int t = threadIdx.x;
    for (int i = t; i < NBINS; i += 256) scnt[i] = 0;
    __syncthreads();
    const int batch = 256 * EPT;
    for (int base = blockIdx.x * batch; base < E; base += gridDim.x * batch) {
        int dd[EPT]; uint ss[EPT]; float ww[EPT]; int ok[EPT];
        #pragma unroll
        for (int k = 0; k < EPT; ++k) {
            int e = base + k * 256 + t;
            ok[k] = (e < E);
            if (ok[k]) { dd[k] = dst[e]; ss[k] = (uint)src[e]; ww[k] = ew[e]; }
        }
        #pragma unroll
        for (int k = 0; k < EPT; ++k) {
            if (!ok[k]) continue;
            int bin = dd[k] >> BINSHIFT;
            int slot = atomicAdd(&scnt[bin], 1);
            if (slot < STAGE_CAP) {
                stage[bin][slot] = make_uint2(
                    ss[k] | ((uint)(dd[k] & (BINW - 1)) << 18),
                    (uint)__float_as_int(ww[k]));
            } else {
                spill_one(dd[k], ss[k], ww[k], spill, spillcnt);  // rare
            }
        }
        __syncthreads();
        for (int bin = t; bin < NBINS; bin += 256) {
            int c = scnt[bin]; if (c > STAGE_CAP) c = STAGE_CAP;
            while (c >= 8) {
                int b0 = atomicAdd(&bincur[bin], 8);
                if (b0 + 8 <= BINCAP) {
                    uint4* o4 = (uint4*)(binbuf + (size_t)bin * BINCAP + b0);
                    uint2* s2 = &stage[bin][c - 8];
                    o4[0] = make_uint4(s2[0].x, s2[0].y, s2[1].x, s2[1].y);
                    o4[1] = make_uint4(s2[2].x, s2[2].y, s2[3].x, s2[3].y);
                    o4[2] = make_uint4(s2[4].x, s2[4].y, s2[5].x, s2[5].y);
                    o4[3] = make_uint4(s2[6].x, s2[6].y, s2[7].x, s2[7].y);
                } else {
                    for (int j = 0; j < 8; ++j) {
                        uint2 r = stage[bin][c - 8 + j];
                        spill_one((bin << BINSHIFT) + (int)(r.x >> 18),
                                  r.x & 0x3FFFFu, __int_as_float((int)r.y),
                                  spill, spillcnt);
                    }
                }
                c -= 8;
            }
            scnt[bin] = c;
        }
        __syncthreads();
    }
    // tail drain: contiguous partial appends (<8 per bin per block)
    for (int bin = t; bin < NBINS; bin += 256) {
        int c = scnt[bin]; if (c > STAGE_CAP) c = STAGE_CAP;
        if (c > 0) {
            int b0 = atomicAdd(&bincur[bin], c);
            for (int j = 0; j < c; ++j) {
                uint2 r = stage[bin][j];
                if (b0 + j < BINCAP) binbuf[(size_t)bin * BINCAP + b0 + j] = r;
                else spill_one((bin << BINSHIFT) + (int)(r.x >> 18),
                               r.x & 0x3FFFFu, __int_as_float((int)r.y),
                               spill, spillcnt);
            }
        }
    }
}

// -------- pass 2: regroup + spills + weighted degree + dinv (all fused) -------
__global__ __launch_bounds__(256) void k_regroup(
        const int* __restrict__ bincur, const uint2* __restrict__ binbuf,
        const uint2* __restrict__ spill, const int* __restrict__ spillcnt,
        uint* __restrict__ recs, int* __restrict__ cursor,
        float* __restrict__ dinv, int4* __restrict__ ovf,
        int* __restrict__ ovfcnt) {
    __shared__ uint image[256 * CAP];   // 47 KB, layout == recs layout
    __shared__ int cnt[256];
    __shared__ float ovfw[256];
    int t = threadIdx.x;
    int bin  = blockIdx.x >> 1;
    int half = blockIdx.x & 1;
    cnt[t] = 0; ovfw[t] = 0.0f;
    __syncthreads();
    int dbase = (bin << BINSHIFT) + half * 256;
    int nrec = bincur[bin]; if (nrec > BINCAP) nrec = BINCAP;
    const uint2* bb = binbuf + (size_t)bin * BINCAP;
    for (int i = t; i < nrec; i += 256) {
        uint2 r = bb[i];
        int dlocal = (int)(r.x >> 18);
        if ((dlocal >> 8) != half) continue;
        int dl = dlocal & 255;
        int slot = atomicAdd(&cnt[dl], 1);
        uint s = r.x & 0x3FFFFu;
        float w = __int_as_float((int)r.y);
        if (slot < CAP) image[dl * CAP + slot] = (q14(w) << 18) | s;
        else {                                              // rare high-degree
            atomicAdd(&ovfw[dl], w);
            int o = atomicAdd(ovfcnt, 1);
            if (o < OVF_MAX)
                ovf[o] = make_int4((bin << BINSHIFT) + dlocal, (int)s,
                                   __float_as_int(w), 0);
        }
    }
    // spill entries (normally ~0)
    int ns = spillcnt[0]; if (ns > SPILL_CAP) ns = SPILL_CAP;
    for (int i = t; i < ns; i += 256) {
        uint2 e = spill[i];
        int d = (int)e.y;
        if (d < dbase || d >= dbase + 256) continue;
        int dl = d - dbase;
        int slot = atomicAdd(&cnt[dl], 1);
        uint s = e.x & 0x3FFFFu;
        uint q = e.x >> 18;
        if (slot < CAP) image[dl * CAP + slot] = (q << 18) | s;
        else {
            float w = (float)q * (1.0f / 16384.0f);
            atomicAdd(&ovfw[dl], w);
            int o = atomicAdd(ovfcnt, 1);
            if (o < OVF_MAX) ovf[o] = make_int4(d, (int)s, __float_as_int(w), 0);
        }
    }
    __syncthreads();
    int ndl = NN - dbase; if (ndl > 256) ndl = 256;
    if (ndl <= 0) return;
    if (t < ndl) {
        int c = cnt[t];
        cursor[dbase + t] = c;
        if (c > CAP) c = CAP;
        uint sq = 0;
        for (int j = 0; j < c; ++j) sq += image[t * CAP + j] >> 18;
        float dg = (float)sq * (1.0f / 16384.0f) + ovfw[t];
        dinv[dbase + t] = rsqrtf(dg + 1.0f);   // self-loop weight 1 folded in
    }
    int tot = ndl * CAP;
    uint* out = recs + (size_t)dbase * CAP;
    for (int i = t; i < tot; i += 256) out[i] = image[i];  // fully coalesced
}

// ------- small GEMM + dinv row-scale, bf16 out: out[n] = bf16(dinv[n]*(row(n)@W)) --
__global__ void k_gemm(const float* __restrict__ h, const float* __restrict__ U,
                       const float* __restrict__ I, const float* __restrict__ W,
                       const float* __restrict__ dinv, ushort* __restrict__ out) {
    __shared__ float Ws[64 * 64];
    for (int i = threadIdx.x; i < 64 * 64; i += blockDim.x) Ws[i] = W[i];
    __syncthreads();
    int lane = threadIdx.x & 63;
    int wpb = blockDim.x >> 6;
    int wid = blockIdx.x * wpb + (threadIdx.x >> 6);
    int tw = gridDim.x * wpb;
    for (int n = wid; n < NN; n += tw) {
        float xv;
        if (h) xv = h[(size_t)n * D + lane];
        else   xv = (n < NU) ? U[(size_t)n * D + lane]
                             : I[(size_t)(n - NU) * D + lane];
        float acc = 0.f;
        #pragma unroll
        for (int k = 0; k < 64; ++k)
            acc = fmaf(lane_bcast(xv, k), Ws[k * 64 + lane], acc);
        out[(size_t)n * D + lane] = f2bf(acc * dinv[n]);
    }
}

// --------- conv accumulate: 2 edges/iter, bpermute broadcast, dword gathers ----
// hw2p = (const uint*)hw2b: row n = 32 dwords, dword p = bf16 feats (2p, 2p+1).
// Lanes 0-31 process even edges, 32-63 odd edges; halves combined at the end.
// Returns float2 = (feat 2p, feat 2p+1), p = lane&31, valid in all lanes.
__device__ __forceinline__ float2 conv_accum2(int n, int lane,
        const uint* __restrict__ hw2p, const int* __restrict__ cursor,
        const uint* __restrict__ recs, const int4* __restrict__ ovf,
        const int* __restrict__ ovfcnt) {
    int cnt = __builtin_amdgcn_readfirstlane(cursor[n]);
    if (cnt > CAP) cnt = CAP;
    uint rv = (lane < cnt) ? recs[(size_t)n * CAP + lane] : 0u;
    int laneoff = lane & 31;
    int ap = ((lane >> 5) & 1) << 2;            // bpermute byte addr: parity*4
    float ax = 0.f, ay = 0.f;
    int cp = (cnt + 1) & ~1;
    for (int j = 0; j < cp; j += 2) {
        uint r = (uint)__builtin_amdgcn_ds_bpermute(ap, (int)rv);
        ap += 8;
        int   s = (int)(r & 0x3FFFFu);
        float w = (float)(r >> 18) * (1.0f / 16384.0f);
        uint x = hw2p[(size_t)s * 32 + laneoff];             // 2 bf16 feats
        ax = fmaf(w, __int_as_float((int)(x << 16)), ax);
        ay = fmaf(w, __int_as_float((int)(x & 0xFFFF0000u)), ay);
    }
    // combine even/odd halves
    ax += __shfl_xor(ax, 32, 64);
    ay += __shfl_xor(ay, 32, 64);
    // self-loop term
    uint xs = hw2p[(size_t)n * 32 + laneoff];
    ax += __int_as_float((int)(xs << 16));
    ay += __int_as_float((int)(xs & 0xFFFF0000u));
    // overflow list (normally empty)
    int novf = __builtin_amdgcn_readfirstlane(ovfcnt[0]);
    if (novf > 0) {
        if (novf > OVF_MAX) novf = OVF_MAX;
        for (int j = 0; j < novf; ++j) {
            int4 e = ovf[j];
            if (e.x == n) {
                float w = __int_as_float(e.z);
                uint x = hw2p[(size_t)e.y * 32 + laneoff];
                ax = fmaf(w, __int_as_float((int)(x << 16)), ax);
                ay = fmaf(w, __int_as_float((int)(x & 0xFFFF0000u)), ay);
            }
        }
    }
    return make_float2(ax, ay);
}

// bias + LN + ReLU on pair layout; returns (y0,y1) for feats (2p, 2p+1)
__device__ __forceinline__ float2 ln_relu2(float2 a, float di, int p,
        const float* __restrict__ b, const float* __restrict__ g,
        const float* __restrict__ be) {
    float2 bb = ((const float2*)b)[p];
    float v0 = fmaf(a.x, di, bb.x);
    float v1 = fmaf(a.y, di, bb.y);
    float m = half_reduce_add(v0 + v1) * (1.0f / 64.0f);
    float d0 = v0 - m, d1 = v1 - m;
    float var = half_reduce_add(d0 * d0 + d1 * d1) * (1.0f / 64.0f);
    float rs = rsqrtf(var + 1e-5f);
    float2 gg = ((const float2*)g)[p];
    float2 ee = ((const float2*)be)[p];
    return make_float2(fmaxf(fmaf(d0 * rs, gg.x, ee.x), 0.0f),
                       fmaxf(fmaf(d1 * rs, gg.y, ee.y), 0.0f));
}

// ---------------- layer-1 conv (all nodes) + bias + LN + ReLU + residual ------
__global__ __launch_bounds__(256) void k_conv1(
        const uint* __restrict__ hw2p, const int* __restrict__ cursor,
        const uint* __restrict__ recs, const int4* __restrict__ ovf,
        const int* __restrict__ ovfcnt, const float* __restrict__ dinv,
        const float* __restrict__ b, const float* __restrict__ g,
        const float* __restrict__ be, const float* __restrict__ U,
        const float* __restrict__ I, float* __restrict__ out) {
    int lane = threadIdx.x & 63;
    int n = __builtin_amdgcn_readfirstlane(blockIdx.x * 4 + (threadIdx.x >> 6));
    if (n >= NN) return;
    float2 a = conv_accum2(n, lane, hw2p, cursor, recs, ovf, ovfcnt);
    int p = lane & 31;
    float2 y = ln_relu2(a, dinv[n], p, b, g, be);
    const float* R = (n < NU) ? (U + (size_t)n * D) : (I + (size_t)(n - NU) * D);
    float2 rr = ((const float2*)R)[p];
    if (lane < 32)
        ((float2*)out)[(size_t)n * 32 + p] = make_float2(y.x + rr.x, y.y + rr.y);
}

// ---------------- layer-2 conv ONLY for sampled nodes -------------------------
__global__ __launch_bounds__(256) void k_conv2s(
        const uint* __restrict__ hw2p, const int* __restrict__ cursor,
        const uint* __restrict__ recs, const int4* __restrict__ ovf,
        const int* __restrict__ ovfcnt, const float* __restrict__ dinv,
        const float* __restrict__ b, const float* __restrict__ g,
        const float* __restrict__ be, const int* __restrict__ users,
        const int* __restrict__ items, const float* __restrict__ h1,
        float* __restrict__ h2s, int B) {
    int lane = threadIdx.x & 63;
    int p = blockIdx.x * 4 + (threadIdx.x >> 6);
    if (p >= 2 * B) return;
    int n = (p < B) ? users[p] : NU + items[p - B];
    n = __builtin_amdgcn_readfirstlane(n);
    float2 a = conv_accum2(n, lane, hw2p, cursor, recs, ovf, ovfcnt);
    int q = lane & 31;
    float2 y = ln_relu2(a, dinv[n], q, b, g, be);
    float2 rr = ((const float2*)h1)[(size_t)n * 32 + q];
    if (lane < 32)
        ((float2*)h2s)[(size_t)p * 32 + q] = make_float2(y.x + rr.x, y.y + rr.y);
}

// ---------------- fused projection + scoring ----------------
__global__ void k_score(const float* __restrict__ h2s, const int* __restrict__ users,
                        const int* __restrict__ items, const float* __restrict__ Wp,
                        const float* __restrict__ bp, const float* __restrict__ bu,
                        const float* __restrict__ bi, const float* __restrict__ mu,
                        float* __restrict__ out, int B) {
    __shared__ float Ws[64 * 64];
    for (int i = threadIdx.x; i < 64 * 64; i += blockDim.x) Ws[i] = Wp[i];
    __syncthreads();
    int lane = threadIdx.x & 63;
    int wpb = blockDim.x >> 6;
    int wid = blockIdx.x * wpb + (threadIdx.x >> 6);
    int tw = gridDim.x * wpb;
    for (int p = wid; p < B; p += tw) {
        float hu = h2s[(size_t)p * D + lane];
        float hi = h2s[(size_t)(B + p) * D + lane];
        float pu = bp[lane], pi = bp[lane];
        #pragma unroll
        for (int k = 0; k < 64; ++k) {
            float wv = Ws[k * 64 + lane];
            pu = fmaf(lane_bcast(hu, k), wv, pu);
            pi = fmaf(lane_bcast(hi, k), wv, pi);
        }
        float t = pu * pi;
        #pragma unroll
        for (int m = 32; m >= 1; m >>= 1) t += __shfl_xor(t, m, 64);
        if (lane == 0) {
            t += bu[users[p]] + bi[items[p]] + mu[0];
            out[p] = fminf(fmaxf(t, 1.0f), 5.0f);
        }
    }
}

extern "C" void kernel_launch(void* const* d_in, const int* in_sizes, int n_in,
                              void* d_out, int out_size, void* d_ws, size_t ws_size,
                              hipStream_t stream) {
    const int*   users = (const int*)d_in[0];
    const int*   items = (const int*)d_in[1];
    const int*   ei2   = (const int*)d_in[2];
    const float* ew    = (const float*)d_in[3];
    const float* U     = (const float*)d_in[4];
    const float* I     = (const float*)d_in[5];
    const float* W0    = (const float*)d_in[6];
    const float* b0    = (const float*)d_in[7];
    const float* g0    = (const float*)d_in[8];
    const float* be0   = (const float*)d_in[9];
    const float* W1    = (const float*)d_in[10];
    const float* b1    = (const float*)d_in[11];
    const float* g1    = (const float*)d_in[12];
    const float* be1   = (const float*)d_in[13];
    const float* Wp    = (const float*)d_in[14];
    const float* bp    = (const float*)d_in[15];
    const float* bu    = (const float*)d_in[16];
    const float* bi    = (const float*)d_in[17];
    const float* mu    = (const float*)d_in[18];

    int B = in_sizes[0];
    int E = in_sizes[2] / 2;
    const int* srcp = ei2;
    const int* dstp = ei2 + E;

    // workspace carve-up (256B aligned); total ~132 MB
    char* p = (char*)d_ws;
    auto alloc = [&](size_t bytes) -> char* {
        char* r = p;
        p += (bytes + 255) & ~(size_t)255;
        return r;
    };
    int*    cbuf    = (int*)  alloc((size_t)(NBINS + 8) * 4);  // bincur|spillcnt|ovfcnt
    int*    bincur  = cbuf;
    int*    spillcnt= cbuf + NBINS;
    int*    ovfcnt  = cbuf + NBINS + 1;
    int*    cursor  = (int*)  alloc((size_t)NN * 4);
    float*  dinv    = (float*)alloc((size_t)NN * 4);
    int4*   ovf     = (int4*) alloc((size_t)OVF_MAX * 16);
    uint2*  spill   = (uint2*)alloc((size_t)SPILL_CAP * 8);      // 2.1 MB
    uint2*  binbuf  = (uint2*)alloc((size_t)NBINS * BINCAP * 8); // 26.8 MB
    uint*   recs    = (uint*) alloc((size_t)NN * CAP * 4);       // 28.2 MB
    ushort* hw2b    = (ushort*)alloc((size_t)NN * D * 2);        // 19.2 MB
    float*  h1      = (float*)alloc((size_t)NN * D * 4);         // 38.4 MB
    float*  h2s     = (float*)alloc((size_t)2 * B * D * 4);      // 16.8 MB
    const uint* hw2p = (const uint*)hw2b;

    hipMemsetAsync(cbuf, 0, (size_t)(NBINS + 8) * 4, stream);

    int gW = (NN + 3) / 4;          // one wave per node, 4 waves/block
    int gS = (2 * B + 3) / 4;       // one wave per sample

    // CSR build: bin -> regroup(+spill+deg+dinv)
    k_bin<<<768, 256, 0, stream>>>(srcp, dstp, ew, bincur, binbuf,
                                   spill, spillcnt, E);
    k_regroup<<<NBINS * 2, 256, 0, stream>>>(bincur, binbuf, spill, spillcnt,
                                             recs, cursor, dinv, ovf, ovfcnt);

    // layer 1 (all nodes)
    k_gemm<<<2048, 256, 0, stream>>>(nullptr, U, I, W0, dinv, hw2b);
    k_conv1<<<gW, 256, 0, stream>>>(hw2p, cursor, recs, ovf, ovfcnt, dinv,
                                    b0, g0, be0, U, I, h1);
    // layer 2 (gemm all nodes; conv only sampled nodes)
    k_gemm<<<2048, 256, 0, stream>>>(h1, U, I, W1, dinv, hw2b);
    k_conv2s<<<gS, 256, 0, stream>>>(hw2p, cursor, recs, ovf, ovfcnt, dinv,
                                     b1, g1, be1, users, items, h1, h2s, B);

    // fused projection + scoring
    k_score<<<512, 256, 0, stream>>>(h2s, users, items, Wp, bp, bu, bi, mu,
                                     (float*)d_out, B);
}

// Round 9
// 456.808 us; speedup vs baseline: 1.1100x; 1.1100x over previous
//
#include <hip/hip_runtime.h>

#define NU 100000
#define NI 50000
#define NN 150000   // NU + NI
#define D  64
#define CAP 47      // bucket capacity per dst; E[max in-degree] ~44 for Poisson(21.3)
#define OVF_MAX 4096

// binning params
#define BINSHIFT 9
#define BINW 512                 // dsts per bin
#define NBINS 293                // ceil(150000/512)
#define BINCAP 11448             // per-bin record cap, multiple of 8
#define STAGE_CAP 20             // LDS stage slots per bin
#define EPT 4                    // edges per thread per batch
#define SPILL_CAP 262144

typedef unsigned int uint;
typedef unsigned short ushort;

// ---------------- helpers ----------------
__device__ __forceinline__ float half_reduce_add(float v) {  // reduce within 32-lane half
    #pragma unroll
    for (int m = 16; m >= 1; m >>= 1) v += __shfl_xor(v, m, 64);
    return v;
}
__device__ __forceinline__ ushort f2bf(float f) {   // round-to-nearest-even
    union { float f; uint i; } c; c.f = f;
    uint r = c.i + 0x7FFF + ((c.i >> 16) & 1);
    return (ushort)(r >> 16);
}
__device__ __forceinline__ float lane_bcast(float v, int l) {
    return __int_as_float(__builtin_amdgcn_readlane(__float_as_int(v), l));
}
__device__ __forceinline__ uint q14(float w) {
    int q = (int)(w * 16384.0f);
    q = (q < 0) ? 0 : (q > 16383 ? 16383 : q);
    return (uint)q;
}
__device__ __forceinline__ void spill_one(int d, uint s, float w,
        uint2* __restrict__ spill, int* __restrict__ spillcnt) {
    int si = atomicAdd(spillcnt, 1);
    if (si < SPILL_CAP) spill[si] = make_uint2(s | (q14(w) << 18), (uint)d);
}

// ---------------- pass 1: LDS-staged binning, line-coalesced flushes ----------
// bin record: word0 = src18 | dlocal9<<18 ; word1 = float weight bits
__global__ __launch_bounds__(256) void k_bin(
        const int* __restrict__ src, const int* __restrict__ dst,
        const float* __restrict__ ew, int* __restrict__ bincur,
        uint2* __restrict__ binbuf, uint2* __restrict__ spill,
        int* __restrict__ spillcnt, int E) {
    __shared__ uint2 stage[NBINS][STAGE_CAP];   // ~47 KB -> 3 blocks/CU
    __shared__ int scnt[NBINS];
    int t = threadIdx.x;
    for (int i = t; i < NBINS; i += 256) scnt[i] = 0;
    __syncthreads();
    const int batch = 256 * EPT;
    for (int base = blockIdx.x * batch; base < E; base += gridDim.x * batch) {
        int dd[EPT]; uint ss[EPT]; float ww[EPT]; int ok[EPT];
        #pragma unroll
        for (int k = 0; k < EPT; ++k) {
            int e = base + k * 256 + t;
            ok[k] = (e < E);
            if (ok[k]) { dd[k] = dst[e]; ss[k] = (uint)src[e]; ww[k] = ew[e]; }
        }
        #pragma unroll
        for (int k = 0; k < EPT; ++k) {
            if (!ok[k]) continue;
            int bin = dd[k] >> BINSHIFT;
            int slot = atomicAdd(&scnt[bin], 1);
            if (slot < STAGE_CAP) {
                stage[bin][slot] = make_uint2(
                    ss[k] | ((uint)(dd[k] & (BINW - 1)) << 18),
                    (uint)__float_as_int(ww[k]));
            } else {
                spill_one(dd[k], ss[k], ww[k], spill, spillcnt);  // rare
            }
        }
        __syncthreads();
        for (int bin = t; bin < NBINS; bin += 256) {
            int c = scnt[bin]; if (c > STAGE_CAP) c = STAGE_CAP;
            while (c >= 8) {
                int b0 = atomicAdd(&bincur[bin], 8);
                if (b0 + 8 <= BINCAP) {
                    uint4* o4 = (uint4*)(binbuf + (size_t)bin * BINCAP + b0);
                    uint2* s2 = &stage[bin][c - 8];
                    o4[0] = make_uint4(s2[0].x, s2[0].y, s2[1].x, s2[1].y);
                    o4[1] = make_uint4(s2[2].x, s2[2].y, s2[3].x, s2[3].y);
                    o4[2] = make_uint4(s2[4].x, s2[4].y, s2[5].x, s2[5].y);
                    o4[3] = make_uint4(s2[6].x, s2[6].y, s2[7].x, s2[7].y);
                } else {
                    for (int j = 0; j < 8; ++j) {
                        uint2 r = stage[bin][c - 8 + j];
                        spill_one((bin << BINSHIFT) + (int)(r.x >> 18),
                                  r.x & 0x3FFFFu, __int_as_float((int)r.y),
                                  spill, spillcnt);
                    }
                }
                c -= 8;
            }
            scnt[bin] = c;
        }
        __syncthreads();
    }
    // tail drain: contiguous partial appends (<8 per bin per block)
    for (int bin = t; bin < NBINS; bin += 256) {
        int c = scnt[bin]; if (c > STAGE_CAP) c = STAGE_CAP;
        if (c > 0) {
            int b0 = atomicAdd(&bincur[bin], c);
            for (int j = 0; j < c; ++j) {
                uint2 r = stage[bin][j];
                if (b0 + j < BINCAP) binbuf[(size_t)bin * BINCAP + b0 + j] = r;
                else spill_one((bin << BINSHIFT) + (int)(r.x >> 18),
                               r.x & 0x3FFFFu, __int_as_float((int)r.y),
                               spill, spillcnt);
            }
        }
    }
}

// -------- pass 2: regroup + spills + weighted degree + dinv (all fused) -------
__global__ __launch_bounds__(256) void k_regroup(
        const int* __restrict__ bincur, const uint2* __restrict__ binbuf,
        const uint2* __restrict__ spill, const int* __restrict__ spillcnt,
        uint* __restrict__ recs, int* __restrict__ cursor,
        float* __restrict__ dinv, int4* __restrict__ ovf,
        int* __restrict__ ovfcnt) {
    __shared__ uint image[256 * CAP];   // 47 KB, layout == recs layout
    __shared__ int cnt[256];
    __shared__ float ovfw[256];
    int t = threadIdx.x;
    int bin  = blockIdx.x >> 1;
    int half = blockIdx.x & 1;
    cnt[t] = 0; ovfw[t] = 0.0f;
    __syncthreads();
    int dbase = (bin << BINSHIFT) + half * 256;
    int nrec = bincur[bin]; if (nrec > BINCAP) nrec = BINCAP;
    const uint2* bb = binbuf + (size_t)bin * BINCAP;
    for (int i = t; i < nrec; i += 256) {
        uint2 r = bb[i];
        int dlocal = (int)(r.x >> 18);
        if ((dlocal >> 8) != half) continue;
        int dl = dlocal & 255;
        int slot = atomicAdd(&cnt[dl], 1);
        uint s = r.x & 0x3FFFFu;
        float w = __int_as_float((int)r.y);
        if (slot < CAP) image[dl * CAP + slot] = (q14(w) << 18) | s;
        else {                                              // rare high-degree
            atomicAdd(&ovfw[dl], w);
            int o = atomicAdd(ovfcnt, 1);
            if (o < OVF_MAX)
                ovf[o] = make_int4((bin << BINSHIFT) + dlocal, (int)s,
                                   __float_as_int(w), 0);
        }
    }
    // spill entries (normally ~0)
    int ns = spillcnt[0]; if (ns > SPILL_CAP) ns = SPILL_CAP;
    for (int i = t; i < ns; i += 256) {
        uint2 e = spill[i];
        int d = (int)e.y;
        if (d < dbase || d >= dbase + 256) continue;
        int dl = d - dbase;
        int slot = atomicAdd(&cnt[dl], 1);
        uint s = e.x & 0x3FFFFu;
        uint q = e.x >> 18;
        if (slot < CAP) image[dl * CAP + slot] = (q << 18) | s;
        else {
            float w = (float)q * (1.0f / 16384.0f);
            atomicAdd(&ovfw[dl], w);
            int o = atomicAdd(ovfcnt, 1);
            if (o < OVF_MAX) ovf[o] = make_int4(d, (int)s, __float_as_int(w), 0);
        }
    }
    __syncthreads();
    int ndl = NN - dbase; if (ndl > 256) ndl = 256;
    if (ndl <= 0) return;
    if (t < ndl) {
        int c = cnt[t];
        cursor[dbase + t] = c;
        if (c > CAP) c = CAP;
        uint sq = 0;
        for (int j = 0; j < c; ++j) sq += image[t * CAP + j] >> 18;
        float dg = (float)sq * (1.0f / 16384.0f) + ovfw[t];
        dinv[dbase + t] = rsqrtf(dg + 1.0f);   // self-loop weight 1 folded in
    }
    int tot = ndl * CAP;
    uint* out = recs + (size_t)dbase * CAP;
    for (int i = t; i < tot; i += 256) out[i] = image[i];  // fully coalesced
}

// ------- small GEMM + dinv row-scale, bf16 out: out[n] = bf16(dinv[n]*(row(n)@W)) --
__global__ void k_gemm(const float* __restrict__ h, const float* __restrict__ U,
                       const float* __restrict__ I, const float* __restrict__ W,
                       const float* __restrict__ dinv, ushort* __restrict__ out) {
    __shared__ float Ws[64 * 64];
    for (int i = threadIdx.x; i < 64 * 64; i += blockDim.x) Ws[i] = W[i];
    __syncthreads();
    int lane = threadIdx.x & 63;
    int wpb = blockDim.x >> 6;
    int wid = blockIdx.x * wpb + (threadIdx.x >> 6);
    int tw = gridDim.x * wpb;
    for (int n = wid; n < NN; n += tw) {
        float xv;
        if (h) xv = h[(size_t)n * D + lane];
        else   xv = (n < NU) ? U[(size_t)n * D + lane]
                             : I[(size_t)(n - NU) * D + lane];
        float acc = 0.f;
        #pragma unroll
        for (int k = 0; k < 64; ++k)
            acc = fmaf(lane_bcast(xv, k), Ws[k * 64 + lane], acc);
        out[(size_t)n * D + lane] = f2bf(acc * dinv[n]);
    }
}

// --- conv accumulate: 2 edges/iter via DOUBLE READLANE (no bpermute), 8-unroll --
// hw2p = (const uint*)hw2b: row n = 32 dwords, dword p = bf16 feats (2p, 2p+1).
// Lanes 0-31 process even edges, 32-63 odd edges; halves combined at the end.
// Returns float2 = (feat 2p, feat 2p+1), p = lane&31, valid in all lanes.
__device__ __forceinline__ float2 conv_accum2(int n, int lane,
        const uint* __restrict__ hw2p, const int* __restrict__ cursor,
        const uint* __restrict__ recs, const int4* __restrict__ ovf,
        const int* __restrict__ ovfcnt) {
    int cnt = __builtin_amdgcn_readfirstlane(cursor[n]);
    if (cnt > CAP) cnt = CAP;
    uint rv = (lane < cnt) ? recs[(size_t)n * CAP + lane] : 0u;
    int odd = lane >> 5;                 // 0: even edges, 1: odd edges
    int laneoff = lane & 31;
    float ax = 0.f, ay = 0.f;
    int cp = (cnt + 7) & ~7;             // pad to chunk of 8 (4 pairs)
    for (int j0 = 0; j0 < cp; j0 += 8) {
        #pragma unroll
        for (int k = 0; k < 4; ++k) {
            // two register-file broadcasts (VALU, no LDS latency), per-half select
            uint re = (uint)__builtin_amdgcn_readlane((int)rv, j0 + 2 * k);
            uint ro = (uint)__builtin_amdgcn_readlane((int)rv, j0 + 2 * k + 1);
            uint r  = odd ? ro : re;                         // v_cndmask
            int   s = (int)(r & 0x3FFFFu);
            float w = (float)(r >> 18) * (1.0f / 16384.0f);
            uint x = hw2p[(size_t)s * 32 + laneoff];         // 2 bf16 feats, 1 load/2 edges
            ax = fmaf(w, __int_as_float((int)(x << 16)), ax);
            ay = fmaf(w, __int_as_float((int)(x & 0xFFFF0000u)), ay);
        }
    }
    // combine even/odd halves
    ax += __shfl_xor(ax, 32, 64);
    ay += __shfl_xor(ay, 32, 64);
    // self-loop term
    uint xs = hw2p[(size_t)n * 32 + laneoff];
    ax += __int_as_float((int)(xs << 16));
    ay += __int_as_float((int)(xs & 0xFFFF0000u));
    // overflow list (normally empty)
    int novf = __builtin_amdgcn_readfirstlane(ovfcnt[0]);
    if (novf > 0) {
        if (novf > OVF_MAX) novf = OVF_MAX;
        for (int j = 0; j < novf; ++j) {
            int4 e = ovf[j];
            if (e.x == n) {
                float w = __int_as_float(e.z);
                uint x = hw2p[(size_t)e.y * 32 + laneoff];
                ax = fmaf(w, __int_as_float((int)(x << 16)), ax);
                ay = fmaf(w, __int_as_float((int)(x & 0xFFFF0000u)), ay);
            }
        }
    }
    return make_float2(ax, ay);
}

// bias + LN + ReLU on pair layout; returns (y0,y1) for feats (2p, 2p+1)
__device__ __forceinline__ float2 ln_relu2(float2 a, float di, int p,
        const float* __restrict__ b, const float* __restrict__ g,
        const float* __restrict__ be) {
    float2 bb = ((const float2*)b)[p];
    float v0 = fmaf(a.x, di, bb.x);
    float v1 = fmaf(a.y, di, bb.y);
    float m = half_reduce_add(v0 + v1) * (1.0f / 64.0f);
    float d0 = v0 - m, d1 = v1 - m;
    float var = half_reduce_add(d0 * d0 + d1 * d1) * (1.0f / 64.0f);
    float rs = rsqrtf(var + 1e-5f);
    float2 gg = ((const float2*)g)[p];
    float2 ee = ((const float2*)be)[p];
    return make_float2(fmaxf(fmaf(d0 * rs, gg.x, ee.x), 0.0f),
                       fmaxf(fmaf(d1 * rs, gg.y, ee.y), 0.0f));
}

// ---------------- layer-1 conv (all nodes) + bias + LN + ReLU + residual ------
__global__ __launch_bounds__(256) void k_conv1(
        const uint* __restrict__ hw2p, const int* __restrict__ cursor,
        const uint* __restrict__ recs, const int4* __restrict__ ovf,
        const int* __restrict__ ovfcnt, const float* __restrict__ dinv,
        const float* __restrict__ b, const float* __restrict__ g,
        const float* __restrict__ be, const float* __restrict__ U,
        const float* __restrict__ I, float* __restrict__ out) {
    int lane = threadIdx.x & 63;
    int n = __builtin_amdgcn_readfirstlane(blockIdx.x * 4 + (threadIdx.x >> 6));
    if (n >= NN) return;
    float2 a = conv_accum2(n, lane, hw2p, cursor, recs, ovf, ovfcnt);
    int p = lane & 31;
    float2 y = ln_relu2(a, dinv[n], p, b, g, be);
    const float* R = (n < NU) ? (U + (size_t)n * D) : (I + (size_t)(n - NU) * D);
    float2 rr = ((const float2*)R)[p];
    if (lane < 32)
        ((float2*)out)[(size_t)n * 32 + p] = make_float2(y.x + rr.x, y.y + rr.y);
}

// ---------------- layer-2 conv ONLY for sampled nodes -------------------------
__global__ __launch_bounds__(256) void k_conv2s(
        const uint* __restrict__ hw2p, const int* __restrict__ cursor,
        const uint* __restrict__ recs, const int4* __restrict__ ovf,
        const int* __restrict__ ovfcnt, const float* __restrict__ dinv,
        const float* __restrict__ b, const float* __restrict__ g,
        const float* __restrict__ be, const int* __restrict__ users,
        const int* __restrict__ items, const float* __restrict__ h1,
        float* __restrict__ h2s, int B) {
    int lane = threadIdx.x & 63;
    int p = blockIdx.x * 4 + (threadIdx.x >> 6);
    if (p >= 2 * B) return;
    int n = (p < B) ? users[p] : NU + items[p - B];
    n = __builtin_amdgcn_readfirstlane(n);
    float2 a = conv_accum2(n, lane, hw2p, cursor, recs, ovf, ovfcnt);
    int q = lane & 31;
    float2 y = ln_relu2(a, dinv[n], q, b, g, be);
    float2 rr = ((const float2*)h1)[(size_t)n * 32 + q];
    if (lane < 32)
        ((float2*)h2s)[(size_t)p * 32 + q] = make_float2(y.x + rr.x, y.y + rr.y);
}

// ---------------- fused projection + scoring ----------------
__global__ void k_score(const float* __restrict__ h2s, const int* __restrict__ users,
                        const int* __restrict__ items, const float* __restrict__ Wp,
                        const float* __restrict__ bp, const float* __restrict__ bu,
                        const float* __restrict__ bi, const float* __restrict__ mu,
                        float* __restrict__ out, int B) {
    __shared__ float Ws[64 * 64];
    for (int i = threadIdx.x; i < 64 * 64; i += blockDim.x) Ws[i] = Wp[i];
    __syncthreads();
    int lane = threadIdx.x & 63;
    int wpb = blockDim.x >> 6;
    int wid = blockIdx.x * wpb + (threadIdx.x >> 6);
    int tw = gridDim.x * wpb;
    for (int p = wid; p < B; p += tw) {
        float hu = h2s[(size_t)p * D + lane];
        float hi = h2s[(size_t)(B + p) * D + lane];
        float pu = bp[lane], pi = bp[lane];
        #pragma unroll
        for (int k = 0; k < 64; ++k) {
            float wv = Ws[k * 64 + lane];
            pu = fmaf(lane_bcast(hu, k), wv, pu);
            pi = fmaf(lane_bcast(hi, k), wv, pi);
        }
        float t = pu * pi;
        #pragma unroll
        for (int m = 32; m >= 1; m >>= 1) t += __shfl_xor(t, m, 64);
        if (lane == 0) {
            t += bu[users[p]] + bi[items[p]] + mu[0];
            out[p] = fminf(fmaxf(t, 1.0f), 5.0f);
        }
    }
}

extern "C" void kernel_launch(void* const* d_in, const int* in_sizes, int n_in,
                              void* d_out, int out_size, void* d_ws, size_t ws_size,
                              hipStream_t stream) {
    const int*   users = (const int*)d_in[0];
    const int*   items = (const int*)d_in[1];
    const int*   ei2   = (const int*)d_in[2];
    const float* ew    = (const float*)d_in[3];
    const float* U     = (const float*)d_in[4];
    const float* I     = (const float*)d_in[5];
    const float* W0    = (const float*)d_in[6];
    const float* b0    = (const float*)d_in[7];
    const float* g0    = (const float*)d_in[8];
    const float* be0   = (const float*)d_in[9];
    const float* W1    = (const float*)d_in[10];
    const float* b1    = (const float*)d_in[11];
    const float* g1    = (const float*)d_in[12];
    const float* be1   = (const float*)d_in[13];
    const float* Wp    = (const float*)d_in[14];
    const float* bp    = (const float*)d_in[15];
    const float* bu    = (const float*)d_in[16];
    const float* bi    = (const float*)d_in[17];
    const float* mu    = (const float*)d_in[18];

    int B = in_sizes[0];
    int E = in_sizes[2] / 2;
    const int* srcp = ei2;
    const int* dstp = ei2 + E;

    // workspace carve-up (256B aligned); total ~132 MB
    char* p = (char*)d_ws;
    auto alloc = [&](size_t bytes) -> char* {
        char* r = p;
        p += (bytes + 255) & ~(size_t)255;
        return r;
    };
    int*    cbuf    = (int*)  alloc((size_t)(NBINS + 8) * 4);  // bincur|spillcnt|ovfcnt
    int*    bincur  = cbuf;
    int*    spillcnt= cbuf + NBINS;
    int*    ovfcnt  = cbuf + NBINS + 1;
    int*    cursor  = (int*)  alloc((size_t)NN * 4);
    float*  dinv    = (float*)alloc((size_t)NN * 4);
    int4*   ovf     = (int4*) alloc((size_t)OVF_MAX * 16);
    uint2*  spill   = (uint2*)alloc((size_t)SPILL_CAP * 8);      // 2.1 MB
    uint2*  binbuf  = (uint2*)alloc((size_t)NBINS * BINCAP * 8); // 26.8 MB
    uint*   recs    = (uint*) alloc((size_t)NN * CAP * 4);       // 28.2 MB
    ushort* hw2b    = (ushort*)alloc((size_t)NN * D * 2);        // 19.2 MB
    float*  h1      = (float*)alloc((size_t)NN * D * 4);         // 38.4 MB
    float*  h2s     = (float*)alloc((size_t)2 * B * D * 4);      // 16.8 MB
    const uint* hw2p = (const uint*)hw2b;

    hipMemsetAsync(cbuf, 0, (size_t)(NBINS + 8) * 4, stream);

    int gW = (NN + 3) / 4;          // one wave per node, 4 waves/block
    int gS = (2 * B + 3) / 4;       // one wave per sample

    // CSR build: bin -> regroup(+spill+deg+dinv)
    k_bin<<<768, 256, 0, stream>>>(srcp, dstp, ew, bincur, binbuf,
                                   spill, spillcnt, E);
    k_regroup<<<NBINS * 2, 256, 0, stream>>>(bincur, binbuf, spill, spillcnt,
                                             recs, cursor, dinv, ovf, ovfcnt);

    // layer 1 (all nodes)
    k_gemm<<<2048, 256, 0, stream>>>(nullptr, U, I, W0, dinv, hw2b);
    k_conv1<<<gW, 256, 0, stream>>>(hw2p, cursor, recs, ovf, ovfcnt, dinv,
                                    b0, g0, be0, U, I, h1);
    // layer 2 (gemm all nodes; conv only sampled nodes)
    k_gemm<<<2048, 256, 0, stream>>>(h1, U, I, W1, dinv, hw2b);
    k_conv2s<<<gS, 256, 0, stream>>>(hw2p, cursor, recs, ovf, ovfcnt, dinv,
                                     b1, g1, be1, users, items, h1, h2s, B);

    // fused projection + scoring
    k_score<<<512, 256, 0, stream>>>(h2s, users, items, Wp, bp, bu, bi, mu,
                                     (float*)d_out, B);
}

// Round 10
// 434.629 us; speedup vs baseline: 1.1667x; 1.0510x over previous
//
#include <hip/hip_runtime.h>

#define NU 100000
#define NI 50000
#define NN 150000   // NU + NI
#define D  64
#define CAP 47      // bucket capacity per dst; E[max in-degree] ~44 for Poisson(21.3)
#define OVF_MAX 4096

// binning params
#define BINSHIFT 9
#define BINW 512                 // dsts per bin
#define NBINS 293                // ceil(150000/512)
#define BINCAP 11448             // per-bin record cap, multiple of 8
#define STAGE_CAP 20             // LDS stage slots per bin
#define EPT 4                    // edges per thread per batch
#define SPILL_CAP 262144

typedef unsigned int uint;
typedef unsigned short ushort;

// ---------------- helpers ----------------
__device__ __forceinline__ float half_reduce_add(float v) {  // reduce within 32-lane half
    #pragma unroll
    for (int m = 16; m >= 1; m >>= 1) v += __shfl_xor(v, m, 64);
    return v;
}
__device__ __forceinline__ ushort f2bf(float f) {   // round-to-nearest-even
    union { float f; uint i; } c; c.f = f;
    uint r = c.i + 0x7FFF + ((c.i >> 16) & 1);
    return (ushort)(r >> 16);
}
__device__ __forceinline__ float lane_bcast(float v, int l) {
    return __int_as_float(__builtin_amdgcn_readlane(__float_as_int(v), l));
}
// bf14 weight encoding: rounded top-14 bits of f32 (w in [0,1)); decode = 1 AND
__device__ __forceinline__ uint enc14(float w) {
    uint b = __float_as_uint(w) + 0x00020000u;   // round at bit 18
    return b & 0xFFFC0000u;
}
__device__ __forceinline__ float dec14(uint r) {
    return __uint_as_float(r & 0xFFFC0000u);
}
__device__ __forceinline__ void spill_one(int d, uint s, float w,
        uint2* __restrict__ spill, int* __restrict__ spillcnt) {
    int si = atomicAdd(spillcnt, 1);
    if (si < SPILL_CAP) spill[si] = make_uint2(s | enc14(w), (uint)d);
}

// ---------------- pass 1: LDS-staged binning, line-coalesced flushes ----------
// bin record: word0 = src18 | dlocal9<<18 ; word1 = float weight bits
__global__ __launch_bounds__(256) void k_bin(
        const int* __restrict__ src, const int* __restrict__ dst,
        const float* __restrict__ ew, int* __restrict__ bincur,
        uint2* __restrict__ binbuf, uint2* __restrict__ spill,
        int* __restrict__ spillcnt, int E) {
    __shared__ uint2 stage[NBINS][STAGE_CAP];   // ~47 KB -> 3 blocks/CU
    __shared__ int scnt[NBINS];
    int t = threadIdx.x;
    for (int i = t; i < NBINS; i += 256) scnt[i] = 0;
    __syncthreads();
    const int batch = 256 * EPT;
    for (int base = blockIdx.x * batch; base < E; base += gridDim.x * batch) {
        int dd[EPT]; uint ss[EPT]; float ww[EPT]; int ok[EPT];
        #pragma unroll
        for (int k = 0; k < EPT; ++k) {
            int e = base + k * 256 + t;
            ok[k] = (e < E);
            if (ok[k]) { dd[k] = dst[e]; ss[k] = (uint)src[e]; ww[k] = ew[e]; }
        }
        #pragma unroll
        for (int k = 0; k < EPT; ++k) {
            if (!ok[k]) continue;
            int bin = dd[k] >> BINSHIFT;
            int slot = atomicAdd(&scnt[bin], 1);
            if (slot < STAGE_CAP) {
                stage[bin][slot] = make_uint2(
                    ss[k] | ((uint)(dd[k] & (BINW - 1)) << 18),
                    (uint)__float_as_int(ww[k]));
            } else {
                spill_one(dd[k], ss[k], ww[k], spill, spillcnt);  // rare
            }
        }
        __syncthreads();
        for (int bin = t; bin < NBINS; bin += 256) {
            int c = scnt[bin]; if (c > STAGE_CAP) c = STAGE_CAP;
            while (c >= 8) {
                int b0 = atomicAdd(&bincur[bin], 8);
                if (b0 + 8 <= BINCAP) {
                    uint4* o4 = (uint4*)(binbuf + (size_t)bin * BINCAP + b0);
                    uint2* s2 = &stage[bin][c - 8];
                    o4[0] = make_uint4(s2[0].x, s2[0].y, s2[1].x, s2[1].y);
                    o4[1] = make_uint4(s2[2].x, s2[2].y, s2[3].x, s2[3].y);
                    o4[2] = make_uint4(s2[4].x, s2[4].y, s2[5].x, s2[5].y);
                    o4[3] = make_uint4(s2[6].x, s2[6].y, s2[7].x, s2[7].y);
                } else {
                    for (int j = 0; j < 8; ++j) {
                        uint2 r = stage[bin][c - 8 + j];
                        spill_one((bin << BINSHIFT) + (int)(r.x >> 18),
                                  r.x & 0x3FFFFu, __int_as_float((int)r.y),
                                  spill, spillcnt);
                    }
                }
                c -= 8;
            }
            scnt[bin] = c;
        }
        __syncthreads();
    }
    // tail drain: contiguous partial appends (<8 per bin per block)
    for (int bin = t; bin < NBINS; bin += 256) {
        int c = scnt[bin]; if (c > STAGE_CAP) c = STAGE_CAP;
        if (c > 0) {
            int b0 = atomicAdd(&bincur[bin], c);
            for (int j = 0; j < c; ++j) {
                uint2 r = stage[bin][j];
                if (b0 + j < BINCAP) binbuf[(size_t)bin * BINCAP + b0 + j] = r;
                else spill_one((bin << BINSHIFT) + (int)(r.x >> 18),
                               r.x & 0x3FFFFu, __int_as_float((int)r.y),
                               spill, spillcnt);
            }
        }
    }
}

// -------- pass 2: regroup + spills + weighted degree + dinv (all fused) -------
__global__ __launch_bounds__(256) void k_regroup(
        const int* __restrict__ bincur, const uint2* __restrict__ binbuf,
        const uint2* __restrict__ spill, const int* __restrict__ spillcnt,
        uint* __restrict__ recs, int* __restrict__ cursor,
        float* __restrict__ dinv, int4* __restrict__ ovf,
        int* __restrict__ ovfcnt) {
    __shared__ uint image[256 * CAP];   // 47 KB, layout == recs layout
    __shared__ int cnt[256];
    __shared__ float ovfw[256];
    int t = threadIdx.x;
    int bin  = blockIdx.x >> 1;
    int half = blockIdx.x & 1;
    cnt[t] = 0; ovfw[t] = 0.0f;
    __syncthreads();
    int dbase = (bin << BINSHIFT) + half * 256;
    int nrec = bincur[bin]; if (nrec > BINCAP) nrec = BINCAP;
    const uint2* bb = binbuf + (size_t)bin * BINCAP;
    for (int i = t; i < nrec; i += 256) {
        uint2 r = bb[i];
        int dlocal = (int)(r.x >> 18);
        if ((dlocal >> 8) != half) continue;
        int dl = dlocal & 255;
        int slot = atomicAdd(&cnt[dl], 1);
        uint s = r.x & 0x3FFFFu;
        float w = __int_as_float((int)r.y);
        if (slot < CAP) image[dl * CAP + slot] = enc14(w) | s;
        else {                                              // rare high-degree
            atomicAdd(&ovfw[dl], w);
            int o = atomicAdd(ovfcnt, 1);
            if (o < OVF_MAX)
                ovf[o] = make_int4((bin << BINSHIFT) + dlocal, (int)s,
                                   __float_as_int(w), 0);
        }
    }
    // spill entries (normally ~0); spill words already bf14-encoded
    int ns = spillcnt[0]; if (ns > SPILL_CAP) ns = SPILL_CAP;
    for (int i = t; i < ns; i += 256) {
        uint2 e = spill[i];
        int d = (int)e.y;
        if (d < dbase || d >= dbase + 256) continue;
        int dl = d - dbase;
        int slot = atomicAdd(&cnt[dl], 1);
        if (slot < CAP) image[dl * CAP + slot] = e.x;
        else {
            float w = dec14(e.x);
            atomicAdd(&ovfw[dl], w);
            int o = atomicAdd(ovfcnt, 1);
            if (o < OVF_MAX) ovf[o] = make_int4(d, (int)(e.x & 0x3FFFFu),
                                                __float_as_int(w), 0);
        }
    }
    __syncthreads();
    int ndl = NN - dbase; if (ndl > 256) ndl = 256;
    if (ndl <= 0) return;
    if (t < ndl) {
        int c = cnt[t];
        cursor[dbase + t] = c;
        if (c > CAP) c = CAP;
        float dg = ovfw[t];
        for (int j = 0; j < c; ++j) dg += dec14(image[t * CAP + j]);
        dinv[dbase + t] = rsqrtf(dg + 1.0f);   // self-loop weight 1 folded in
    }
    int tot = ndl * CAP;
    uint* out = recs + (size_t)dbase * CAP;
    for (int i = t; i < tot; i += 256) out[i] = image[i];  // fully coalesced
}

// ------- small GEMM + dinv row-scale, bf16 out; W held in VGPRs (no LDS) -------
__global__ __launch_bounds__(256) void k_gemm(
        const float* __restrict__ h, const float* __restrict__ U,
        const float* __restrict__ I, const float* __restrict__ W,
        const float* __restrict__ dinv, ushort* __restrict__ out) {
    int lane = threadIdx.x & 63;
    float wreg[64];                         // column `lane` of W, 64 VGPRs
    #pragma unroll
    for (int k = 0; k < 64; ++k) wreg[k] = W[k * 64 + lane];
    int wpb = blockDim.x >> 6;
    int wid = blockIdx.x * wpb + (threadIdx.x >> 6);
    int tw = gridDim.x * wpb;
    for (int n = wid; n < NN; n += tw) {
        float xv;
        if (h) xv = h[(size_t)n * D + lane];
        else   xv = (n < NU) ? U[(size_t)n * D + lane]
                             : I[(size_t)(n - NU) * D + lane];
        float acc = 0.f;
        #pragma unroll
        for (int k = 0; k < 64; ++k)
            acc = fmaf(lane_bcast(xv, k), wreg[k], acc);
        out[(size_t)n * D + lane] = f2bf(acc * dinv[n]);
    }
}

// --- conv accumulate: 2 edges/iter via double readlane, bf14 1-op decode ------
// hw2p = (const uint*)hw2b: row n = 32 dwords, dword p = bf16 feats (2p, 2p+1).
// Lanes 0-31 process even edges, 32-63 odd edges; halves combined at the end.
__device__ __forceinline__ float2 conv_accum2(int n, int lane,
        const uint* __restrict__ hw2p, const int* __restrict__ cursor,
        const uint* __restrict__ recs, const int4* __restrict__ ovf,
        const int* __restrict__ ovfcnt) {
    int cnt = __builtin_amdgcn_readfirstlane(cursor[n]);
    if (cnt > CAP) cnt = CAP;
    uint rv = (lane < cnt) ? recs[(size_t)n * CAP + lane] : 0u;
    int odd = lane >> 5;                 // 0: even edges, 1: odd edges
    int laneoff = lane & 31;
    float ax = 0.f, ay = 0.f;
    int cp = (cnt + 7) & ~7;             // pad to chunk of 8 (4 pairs)
    for (int j0 = 0; j0 < cp; j0 += 8) {
        #pragma unroll
        for (int k = 0; k < 4; ++k) {
            uint re = (uint)__builtin_amdgcn_readlane((int)rv, j0 + 2 * k);
            uint ro = (uint)__builtin_amdgcn_readlane((int)rv, j0 + 2 * k + 1);
            uint r  = odd ? ro : re;                         // v_cndmask
            int   s = (int)(r & 0x3FFFFu);
            float w = dec14(r);                              // 1 AND
            uint x = hw2p[(size_t)s * 32 + laneoff];         // 2 bf16 feats
            ax = fmaf(w, __int_as_float((int)(x << 16)), ax);
            ay = fmaf(w, __int_as_float((int)(x & 0xFFFF0000u)), ay);
        }
    }
    // combine even/odd halves
    ax += __shfl_xor(ax, 32, 64);
    ay += __shfl_xor(ay, 32, 64);
    // self-loop term
    uint xs = hw2p[(size_t)n * 32 + laneoff];
    ax += __int_as_float((int)(xs << 16));
    ay += __int_as_float((int)(xs & 0xFFFF0000u));
    // overflow list (normally empty)
    int novf = __builtin_amdgcn_readfirstlane(ovfcnt[0]);
    if (novf > 0) {
        if (novf > OVF_MAX) novf = OVF_MAX;
        for (int j = 0; j < novf; ++j) {
            int4 e = ovf[j];
            if (e.x == n) {
                float w = __int_as_float(e.z);
                uint x = hw2p[(size_t)e.y * 32 + laneoff];
                ax = fmaf(w, __int_as_float((int)(x << 16)), ax);
                ay = fmaf(w, __int_as_float((int)(x & 0xFFFF0000u)), ay);
            }
        }
    }
    return make_float2(ax, ay);
}

// bias + LN + ReLU on pair layout; returns (y0,y1) for feats (2p, 2p+1)
__device__ __forceinline__ float2 ln_relu2(float2 a, float di, int p,
        const float* __restrict__ b, const float* __restrict__ g,
        const float* __restrict__ be) {
    float2 bb = ((const float2*)b)[p];
    float v0 = fmaf(a.x, di, bb.x);
    float v1 = fmaf(a.y, di, bb.y);
    float m = half_reduce_add(v0 + v1) * (1.0f / 64.0f);
    float d0 = v0 - m, d1 = v1 - m;
    float var = half_reduce_add(d0 * d0 + d1 * d1) * (1.0f / 64.0f);
    float rs = rsqrtf(var + 1e-5f);
    float2 gg = ((const float2*)g)[p];
    float2 ee = ((const float2*)be)[p];
    return make_float2(fmaxf(fmaf(d0 * rs, gg.x, ee.x), 0.0f),
                       fmaxf(fmaf(d1 * rs, gg.y, ee.y), 0.0f));
}

// ---------------- layer-1 conv (all nodes) + bias + LN + ReLU + residual ------
__global__ __launch_bounds__(256) void k_conv1(
        const uint* __restrict__ hw2p, const int* __restrict__ cursor,
        const uint* __restrict__ recs, const int4* __restrict__ ovf,
        const int* __restrict__ ovfcnt, const float* __restrict__ dinv,
        const float* __restrict__ b, const float* __restrict__ g,
        const float* __restrict__ be, const float* __restrict__ U,
        const float* __restrict__ I, float* __restrict__ out) {
    int lane = threadIdx.x & 63;
    int n = __builtin_amdgcn_readfirstlane(blockIdx.x * 4 + (threadIdx.x >> 6));
    if (n >= NN) return;
    float2 a = conv_accum2(n, lane, hw2p, cursor, recs, ovf, ovfcnt);
    int p = lane & 31;
    float2 y = ln_relu2(a, dinv[n], p, b, g, be);
    const float* R = (n < NU) ? (U + (size_t)n * D) : (I + (size_t)(n - NU) * D);
    float2 rr = ((const float2*)R)[p];
    if (lane < 32)
        ((float2*)out)[(size_t)n * 32 + p] = make_float2(y.x + rr.x, y.y + rr.y);
}

// ---------------- layer-2 conv ONLY for sampled nodes -------------------------
__global__ __launch_bounds__(256) void k_conv2s(
        const uint* __restrict__ hw2p, const int* __restrict__ cursor,
        const uint* __restrict__ recs, const int4* __restrict__ ovf,
        const int* __restrict__ ovfcnt, const float* __restrict__ dinv,
        const float* __restrict__ b, const float* __restrict__ g,
        const float* __restrict__ be, const int* __restrict__ users,
        const int* __restrict__ items, const float* __restrict__ h1,
        float* __restrict__ h2s, int B) {
    int lane = threadIdx.x & 63;
    int p = blockIdx.x * 4 + (threadIdx.x >> 6);
    if (p >= 2 * B) return;
    int n = (p < B) ? users[p] : NU + items[p - B];
    n = __builtin_amdgcn_readfirstlane(n);
    float2 a = conv_accum2(n, lane, hw2p, cursor, recs, ovf, ovfcnt);
    int q = lane & 31;
    float2 y = ln_relu2(a, dinv[n], q, b, g, be);
    float2 rr = ((const float2*)h1)[(size_t)n * 32 + q];
    if (lane < 32)
        ((float2*)h2s)[(size_t)p * 32 + q] = make_float2(y.x + rr.x, y.y + rr.y);
}

// ---------------- fused projection + scoring; Wp held in VGPRs ----------------
__global__ __launch_bounds__(256) void k_score(
        const float* __restrict__ h2s, const int* __restrict__ users,
        const int* __restrict__ items, const float* __restrict__ Wp,
        const float* __restrict__ bp, const float* __restrict__ bu,
        const float* __restrict__ bi, const float* __restrict__ mu,
        float* __restrict__ out, int B) {
    int lane = threadIdx.x & 63;
    float wreg[64];                         // column `lane` of Wp
    #pragma unroll
    for (int k = 0; k < 64; ++k) wreg[k] = Wp[k * 64 + lane];
    float bpl = bp[lane];
    int wpb = blockDim.x >> 6;
    int wid = blockIdx.x * wpb + (threadIdx.x >> 6);
    int tw = gridDim.x * wpb;
    for (int p = wid; p < B; p += tw) {
        float hu = h2s[(size_t)p * D + lane];
        float hi = h2s[(size_t)(B + p) * D + lane];
        float pu = bpl, pi = bpl;
        #pragma unroll
        for (int k = 0; k < 64; ++k) {
            float wv = wreg[k];
            pu = fmaf(lane_bcast(hu, k), wv, pu);
            pi = fmaf(lane_bcast(hi, k), wv, pi);
        }
        float t = pu * pi;
        #pragma unroll
        for (int m = 32; m >= 1; m >>= 1) t += __shfl_xor(t, m, 64);
        if (lane == 0) {
            t += bu[users[p]] + bi[items[p]] + mu[0];
            out[p] = fminf(fmaxf(t, 1.0f), 5.0f);
        }
    }
}

extern "C" void kernel_launch(void* const* d_in, const int* in_sizes, int n_in,
                              void* d_out, int out_size, void* d_ws, size_t ws_size,
                              hipStream_t stream) {
    const int*   users = (const int*)d_in[0];
    const int*   items = (const int*)d_in[1];
    const int*   ei2   = (const int*)d_in[2];
    const float* ew    = (const float*)d_in[3];
    const float* U     = (const float*)d_in[4];
    const float* I     = (const float*)d_in[5];
    const float* W0    = (const float*)d_in[6];
    const float* b0    = (const float*)d_in[7];
    const float* g0    = (const float*)d_in[8];
    const float* be0   = (const float*)d_in[9];
    const float* W1    = (const float*)d_in[10];
    const float* b1    = (const float*)d_in[11];
    const float* g1    = (const float*)d_in[12];
    const float* be1   = (const float*)d_in[13];
    const float* Wp    = (const float*)d_in[14];
    const float* bp    = (const float*)d_in[15];
    const float* bu    = (const float*)d_in[16];
    const float* bi    = (const float*)d_in[17];
    const float* mu    = (const float*)d_in[18];

    int B = in_sizes[0];
    int E = in_sizes[2] / 2;
    const int* srcp = ei2;
    const int* dstp = ei2 + E;

    // workspace carve-up (256B aligned); total ~132 MB
    char* p = (char*)d_ws;
    auto alloc = [&](size_t bytes) -> char* {
        char* r = p;
        p += (bytes + 255) & ~(size_t)255;
        return r;
    };
    int*    cbuf    = (int*)  alloc((size_t)(NBINS + 8) * 4);  // bincur|spillcnt|ovfcnt
    int*    bincur  = cbuf;
    int*    spillcnt= cbuf + NBINS;
    int*    ovfcnt  = cbuf + NBINS + 1;
    int*    cursor  = (int*)  alloc((size_t)NN * 4);
    float*  dinv    = (float*)alloc((size_t)NN * 4);
    int4*   ovf     = (int4*) alloc((size_t)OVF_MAX * 16);
    uint2*  spill   = (uint2*)alloc((size_t)SPILL_CAP * 8);      // 2.1 MB
    uint2*  binbuf  = (uint2*)alloc((size_t)NBINS * BINCAP * 8); // 26.8 MB
    uint*   recs    = (uint*) alloc((size_t)NN * CAP * 4);       // 28.2 MB
    ushort* hw2b    = (ushort*)alloc((size_t)NN * D * 2);        // 19.2 MB
    float*  h1      = (float*)alloc((size_t)NN * D * 4);         // 38.4 MB
    float*  h2s     = (float*)alloc((size_t)2 * B * D * 4);      // 16.8 MB
    const uint* hw2p = (const uint*)hw2b;

    hipMemsetAsync(cbuf, 0, (size_t)(NBINS + 8) * 4, stream);

    int gW = (NN + 3) / 4;          // one wave per node, 4 waves/block
    int gS = (2 * B + 3) / 4;       // one wave per sample

    // CSR build: bin -> regroup(+spill+deg+dinv)
    k_bin<<<768, 256, 0, stream>>>(srcp, dstp, ew, bincur, binbuf,
                                   spill, spillcnt, E);
    k_regroup<<<NBINS * 2, 256, 0, stream>>>(bincur, binbuf, spill, spillcnt,
                                             recs, cursor, dinv, ovf, ovfcnt);

    // layer 1 (all nodes)
    k_gemm<<<2048, 256, 0, stream>>>(nullptr, U, I, W0, dinv, hw2b);
    k_conv1<<<gW, 256, 0, stream>>>(hw2p, cursor, recs, ovf, ovfcnt, dinv,
                                    b0, g0, be0, U, I, h1);
    // layer 2 (gemm all nodes; conv only sampled nodes)
    k_gemm<<<2048, 256, 0, stream>>>(h1, U, I, W1, dinv, hw2b);
    k_conv2s<<<gS, 256, 0, stream>>>(hw2p, cursor, recs, ovf, ovfcnt, dinv,
                                     b1, g1, be1, users, items, h1, h2s, B);

    // fused projection + scoring
    k_score<<<512, 256, 0, stream>>>(h2s, users, items, Wp, bp, bu, bi, mu,
                                     (float*)d_out, B);
}

// Round 11
// 434.480 us; speedup vs baseline: 1.1671x; 1.0003x over previous
//
#include <hip/hip_runtime.h>

#define NU 100000
#define NI 50000
#define NN 150000   // NU + NI
#define D  64
#define CAP 47      // bucket capacity per dst; E[max in-degree] ~44 for Poisson(21.3)
#define OVF_MAX 4096

// binning params (256-wide bins: regroup block reads exactly its own records)
#define BINSHIFT 8
#define BINW 256                 // dsts per bin
#define NBINS 586                // ceil(150000/256); 586*256 = 150016
#define BINCAP 5848              // per-bin record cap (mean 5461 + 5 sigma), mult of 8
#define STAGE_CAP 12             // LDS stage slots per bin
#define EPT 4                    // edges per thread per batch
#define SPILL_CAP 262144

typedef unsigned int uint;
typedef unsigned short ushort;

// ---------------- helpers ----------------
__device__ __forceinline__ ushort f2bf(float f) {   // round-to-nearest-even
    union { float f; uint i; } c; c.f = f;
    uint r = c.i + 0x7FFF + ((c.i >> 16) & 1);
    return (ushort)(r >> 16);
}
__device__ __forceinline__ float lane_bcast(float v, int l) {
    return __int_as_float(__builtin_amdgcn_readlane(__float_as_int(v), l));
}
__device__ __forceinline__ float bflo(uint u) {
    return __int_as_float((int)(u << 16));
}
__device__ __forceinline__ float bfhi(uint u) {
    return __int_as_float((int)(u & 0xFFFF0000u));
}
// bf14 weight encoding: rounded top-14 bits of f32 (w in [0,1)); decode = 1 AND
__device__ __forceinline__ uint enc14(float w) {
    uint b = __float_as_uint(w) + 0x00020000u;   // round at bit 18
    return b & 0xFFFC0000u;
}
__device__ __forceinline__ float dec14(uint r) {
    return __uint_as_float(r & 0xFFFC0000u);
}
__device__ __forceinline__ void spill_one(int d, uint s, float w,
        uint2* __restrict__ spill, int* __restrict__ spillcnt) {
    int si = atomicAdd(spillcnt, 1);
    if (si < SPILL_CAP) spill[si] = make_uint2(s | enc14(w), (uint)d);
}

// ---------------- pass 1: LDS-staged binning, line-coalesced flushes ----------
// bin record: word0 = src18 | dlocal8<<18 ; word1 = float weight bits
__global__ __launch_bounds__(256) void k_bin(
        const int* __restrict__ src, const int* __restrict__ dst,
        const float* __restrict__ ew, int* __restrict__ bincur,
        uint2* __restrict__ binbuf, uint2* __restrict__ spill,
        int* __restrict__ spillcnt, int E) {
    __shared__ uint2 stage[NBINS][STAGE_CAP];   // ~56 KB -> 2 blocks/CU
    __shared__ int scnt[NBINS];
    int t = threadIdx.x;
    for (int i = t; i < NBINS; i += 256) scnt[i] = 0;
    __syncthreads();
    const int batch = 256 * EPT;
    for (int base = blockIdx.x * batch; base < E; base += gridDim.x * batch) {
        int dd[EPT]; uint ss[EPT]; float ww[EPT]; int ok[EPT];
        #pragma unroll
        for (int k = 0; k < EPT; ++k) {
            int e = base + k * 256 + t;
            ok[k] = (e < E);
            if (ok[k]) { dd[k] = dst[e]; ss[k] = (uint)src[e]; ww[k] = ew[e]; }
        }
        #pragma unroll
        for (int k = 0; k < EPT; ++k) {
            if (!ok[k]) continue;
            int bin = dd[k] >> BINSHIFT;
            int slot = atomicAdd(&scnt[bin], 1);
            if (slot < STAGE_CAP) {
                stage[bin][slot] = make_uint2(
                    ss[k] | ((uint)(dd[k] & (BINW - 1)) << 18),
                    (uint)__float_as_int(ww[k]));
            } else {
                spill_one(dd[k], ss[k], ww[k], spill, spillcnt);  // rare
            }
        }
        __syncthreads();
        for (int bin = t; bin < NBINS; bin += 256) {
            int c = scnt[bin]; if (c > STAGE_CAP) c = STAGE_CAP;
            while (c >= 8) {
                int b0 = atomicAdd(&bincur[bin], 8);
                if (b0 + 8 <= BINCAP) {
                    uint4* o4 = (uint4*)(binbuf + (size_t)bin * BINCAP + b0);
                    uint2* s2 = &stage[bin][c - 8];
                    o4[0] = make_uint4(s2[0].x, s2[0].y, s2[1].x, s2[1].y);
                    o4[1] = make_uint4(s2[2].x, s2[2].y, s2[3].x, s2[3].y);
                    o4[2] = make_uint4(s2[4].x, s2[4].y, s2[5].x, s2[5].y);
                    o4[3] = make_uint4(s2[6].x, s2[6].y, s2[7].x, s2[7].y);
                } else {
                    for (int j = 0; j < 8; ++j) {
                        uint2 r = stage[bin][c - 8 + j];
                        spill_one((bin << BINSHIFT) + (int)(r.x >> 18),
                                  r.x & 0x3FFFFu, __int_as_float((int)r.y),
                                  spill, spillcnt);
                    }
                }
                c -= 8;
            }
            scnt[bin] = c;
        }
        __syncthreads();
    }
    // tail drain: contiguous partial appends (<8 per bin per block)
    for (int bin = t; bin < NBINS; bin += 256) {
        int c = scnt[bin]; if (c > STAGE_CAP) c = STAGE_CAP;
        if (c > 0) {
            int b0 = atomicAdd(&bincur[bin], c);
            for (int j = 0; j < c; ++j) {
                uint2 r = stage[bin][j];
                if (b0 + j < BINCAP) binbuf[(size_t)bin * BINCAP + b0 + j] = r;
                else spill_one((bin << BINSHIFT) + (int)(r.x >> 18),
                               r.x & 0x3FFFFu, __int_as_float((int)r.y),
                               spill, spillcnt);
            }
        }
    }
}

// -------- pass 2: regroup + spills + weighted degree + dinv (one block/bin) ---
__global__ __launch_bounds__(256) void k_regroup(
        const int* __restrict__ bincur, const uint2* __restrict__ binbuf,
        const uint2* __restrict__ spill, const int* __restrict__ spillcnt,
        uint* __restrict__ recs, int* __restrict__ cursor,
        float* __restrict__ dinv, int4* __restrict__ ovf,
        int* __restrict__ ovfcnt) {
    __shared__ uint image[256 * CAP];   // 47 KB, layout == recs layout
    __shared__ int cnt[256];
    __shared__ float ovfw[256];
    int t = threadIdx.x;
    int bin = blockIdx.x;
    cnt[t] = 0; ovfw[t] = 0.0f;
    __syncthreads();
    int dbase = bin << BINSHIFT;
    int nrec = bincur[bin]; if (nrec > BINCAP) nrec = BINCAP;
    const uint2* bb = binbuf + (size_t)bin * BINCAP;
    for (int i = t; i < nrec; i += 256) {
        uint2 r = bb[i];
        int dl = (int)(r.x >> 18);          // 8-bit dlocal, top bits zero
        int slot = atomicAdd(&cnt[dl], 1);
        uint s = r.x & 0x3FFFFu;
        float w = __int_as_float((int)r.y);
        if (slot < CAP) image[dl * CAP + slot] = enc14(w) | s;
        else {                                              // rare high-degree
            atomicAdd(&ovfw[dl], w);
            int o = atomicAdd(ovfcnt, 1);
            if (o < OVF_MAX)
                ovf[o] = make_int4(dbase + dl, (int)s, __float_as_int(w), 0);
        }
    }
    // spill entries (normally ~0); spill words already bf14-encoded
    int ns = spillcnt[0]; if (ns > SPILL_CAP) ns = SPILL_CAP;
    for (int i = t; i < ns; i += 256) {
        uint2 e = spill[i];
        int d = (int)e.y;
        if (d < dbase || d >= dbase + BINW) continue;
        int dl = d - dbase;
        int slot = atomicAdd(&cnt[dl], 1);
        if (slot < CAP) image[dl * CAP + slot] = e.x;
        else {
            float w = dec14(e.x);
            atomicAdd(&ovfw[dl], w);
            int o = atomicAdd(ovfcnt, 1);
            if (o < OVF_MAX) ovf[o] = make_int4(d, (int)(e.x & 0x3FFFFu),
                                                __float_as_int(w), 0);
        }
    }
    __syncthreads();
    int ndl = NN - dbase; if (ndl > 256) ndl = 256;
    if (ndl <= 0) return;
    if (t < ndl) {
        int c = cnt[t];
        cursor[dbase + t] = c;
        if (c > CAP) c = CAP;
        float dg = ovfw[t];
        for (int j = 0; j < c; ++j) dg += dec14(image[t * CAP + j]);
        dinv[dbase + t] = rsqrtf(dg + 1.0f);   // self-loop weight 1 folded in
    }
    int tot = ndl * CAP;
    uint* out = recs + (size_t)dbase * CAP;
    for (int i = t; i < tot; i += 256) out[i] = image[i];  // fully coalesced
}

// ------- small GEMM + dinv row-scale, bf16 out; W held in VGPRs (no LDS) -------
__global__ __launch_bounds__(256) void k_gemm(
        const float* __restrict__ h, const float* __restrict__ U,
        const float* __restrict__ I, const float* __restrict__ W,
        const float* __restrict__ dinv, ushort* __restrict__ out) {
    int lane = threadIdx.x & 63;
    float wreg[64];                         // column `lane` of W, 64 VGPRs
    #pragma unroll
    for (int k = 0; k < 64; ++k) wreg[k] = W[k * 64 + lane];
    int wpb = blockDim.x >> 6;
    int wid = blockIdx.x * wpb + (threadIdx.x >> 6);
    int tw = gridDim.x * wpb;
    for (int n = wid; n < NN; n += tw) {
        float xv;
        if (h) xv = h[(size_t)n * D + lane];
        else   xv = (n < NU) ? U[(size_t)n * D + lane]
                             : I[(size_t)(n - NU) * D + lane];
        float acc = 0.f;
        #pragma unroll
        for (int k = 0; k < 64; ++k)
            acc = fmaf(lane_bcast(xv, k), wreg[k], acc);
        out[(size_t)n * D + lane] = f2bf(acc * dinv[n]);
    }
}

// --- conv accumulate: 4 edges/iter, 16 lanes/edge, uint2 (8B) gathers ---------
// hw2q = (const uint2*)hw2b: row n = 16 uint2; uint2 at loff = bf16 feats
// (4*loff .. 4*loff+3). Quarter q = lane>>4 processes edge j0+q.
// Returns float4 = feats (4*loff..4*loff+3), loff = lane&15, valid in all lanes.
__device__ __forceinline__ float4 conv_accum4(int n, int lane,
        const uint2* __restrict__ hw2q, const int* __restrict__ cursor,
        const uint* __restrict__ recs, const int4* __restrict__ ovf,
        const int* __restrict__ ovfcnt) {
    int cnt = __builtin_amdgcn_readfirstlane(cursor[n]);
    if (cnt > CAP) cnt = CAP;
    uint rv = (lane < cnt) ? recs[(size_t)n * CAP + lane] : 0u;
    int loff = lane & 15;
    bool b4 = (lane & 16) != 0, b5 = (lane & 32) != 0;
    float ax = 0.f, ay = 0.f, az = 0.f, aw = 0.f;
    int cp = (cnt + 3) & ~3;             // pad to chunk of 4
    for (int j0 = 0; j0 < cp; j0 += 4) {
        uint r0 = (uint)__builtin_amdgcn_readlane((int)rv, j0);
        uint r1 = (uint)__builtin_amdgcn_readlane((int)rv, j0 + 1);
        uint r2 = (uint)__builtin_amdgcn_readlane((int)rv, j0 + 2);
        uint r3 = (uint)__builtin_amdgcn_readlane((int)rv, j0 + 3);
        uint ra = b5 ? r3 : r1;
        uint rb = b5 ? r2 : r0;
        uint r  = b4 ? ra : rb;          // quarter q gets edge j0+q
        int   s = (int)(r & 0x3FFFFu);
        float w = dec14(r);              // 1 AND
        uint2 x = hw2q[(size_t)s * 16 + loff];   // 8 B: 4 bf16 feats
        ax = fmaf(w, bflo(x.x), ax);
        ay = fmaf(w, bfhi(x.x), ay);
        az = fmaf(w, bflo(x.y), az);
        aw = fmaf(w, bfhi(x.y), aw);
    }
    // combine 4 quarters
    ax += __shfl_xor(ax, 32, 64); ay += __shfl_xor(ay, 32, 64);
    az += __shfl_xor(az, 32, 64); aw += __shfl_xor(aw, 32, 64);
    ax += __shfl_xor(ax, 16, 64); ay += __shfl_xor(ay, 16, 64);
    az += __shfl_xor(az, 16, 64); aw += __shfl_xor(aw, 16, 64);
    // self-loop term
    uint2 xs = hw2q[(size_t)n * 16 + loff];
    ax += bflo(xs.x); ay += bfhi(xs.x); az += bflo(xs.y); aw += bfhi(xs.y);
    // overflow list (normally empty)
    int novf = __builtin_amdgcn_readfirstlane(ovfcnt[0]);
    if (novf > 0) {
        if (novf > OVF_MAX) novf = OVF_MAX;
        for (int j = 0; j < novf; ++j) {
            int4 e = ovf[j];
            if (e.x == n) {
                float w = __int_as_float(e.z);
                uint2 x = hw2q[(size_t)e.y * 16 + loff];
                ax = fmaf(w, bflo(x.x), ax); ay = fmaf(w, bfhi(x.x), ay);
                az = fmaf(w, bflo(x.y), az); aw = fmaf(w, bfhi(x.y), aw);
            }
        }
    }
    return make_float4(ax, ay, az, aw);
}

// bias + LN + ReLU on quad layout; feats (4*loff..4*loff+3)
__device__ __forceinline__ float4 ln_relu4(float4 a, float di, int loff,
        const float* __restrict__ b, const float* __restrict__ g,
        const float* __restrict__ be) {
    float4 bb = ((const float4*)b)[loff];
    float v0 = fmaf(a.x, di, bb.x);
    float v1 = fmaf(a.y, di, bb.y);
    float v2 = fmaf(a.z, di, bb.z);
    float v3 = fmaf(a.w, di, bb.w);
    float s = v0 + v1 + v2 + v3;
    #pragma unroll
    for (int m = 8; m >= 1; m >>= 1) s += __shfl_xor(s, m, 64);
    float mean = s * (1.0f / 64.0f);
    float d0 = v0 - mean, d1 = v1 - mean, d2 = v2 - mean, d3 = v3 - mean;
    float vs = d0 * d0 + d1 * d1 + d2 * d2 + d3 * d3;
    #pragma unroll
    for (int m = 8; m >= 1; m >>= 1) vs += __shfl_xor(vs, m, 64);
    float rs = rsqrtf(vs * (1.0f / 64.0f) + 1e-5f);
    float4 gg = ((const float4*)g)[loff];
    float4 ee = ((const float4*)be)[loff];
    return make_float4(fmaxf(fmaf(d0 * rs, gg.x, ee.x), 0.0f),
                       fmaxf(fmaf(d1 * rs, gg.y, ee.y), 0.0f),
                       fmaxf(fmaf(d2 * rs, gg.z, ee.z), 0.0f),
                       fmaxf(fmaf(d3 * rs, gg.w, ee.w), 0.0f));
}

// ---------------- layer-1 conv (all nodes) + bias + LN + ReLU + residual ------
__global__ __launch_bounds__(256) void k_conv1(
        const uint2* __restrict__ hw2q, const int* __restrict__ cursor,
        const uint* __restrict__ recs, const int4* __restrict__ ovf,
        const int* __restrict__ ovfcnt, const float* __restrict__ dinv,
        const float* __restrict__ b, const float* __restrict__ g,
        const float* __restrict__ be, const float* __restrict__ U,
        const float* __restrict__ I, float* __restrict__ out) {
    int lane = threadIdx.x & 63;
    int n = __builtin_amdgcn_readfirstlane(blockIdx.x * 4 + (threadIdx.x >> 6));
    if (n >= NN) return;
    float4 a = conv_accum4(n, lane, hw2q, cursor, recs, ovf, ovfcnt);
    int loff = lane & 15;
    float4 y = ln_relu4(a, dinv[n], loff, b, g, be);
    const float* R = (n < NU) ? (U + (size_t)n * D) : (I + (size_t)(n - NU) * D);
    float4 rr = ((const float4*)R)[loff];
    if (lane < 16)
        ((float4*)out)[(size_t)n * 16 + loff] =
            make_float4(y.x + rr.x, y.y + rr.y, y.z + rr.z, y.w + rr.w);
}

// ---------------- layer-2 conv ONLY for sampled nodes -------------------------
__global__ __launch_bounds__(256) void k_conv2s(
        const uint2* __restrict__ hw2q, const int* __restrict__ cursor,
        const uint* __restrict__ recs, const int4* __restrict__ ovf,
        const int* __restrict__ ovfcnt, const float* __restrict__ dinv,
        const float* __restrict__ b, const float* __restrict__ g,
        const float* __restrict__ be, const int* __restrict__ users,
        const int* __restrict__ items, const float* __restrict__ h1,
        float* __restrict__ h2s, int B) {
    int lane = threadIdx.x & 63;
    int p = blockIdx.x * 4 + (threadIdx.x >> 6);
    if (p >= 2 * B) return;
    int n = (p < B) ? users[p] : NU + items[p - B];
    n = __builtin_amdgcn_readfirstlane(n);
    float4 a = conv_accum4(n, lane, hw2q, cursor, recs, ovf, ovfcnt);
    int loff = lane & 15;
    float4 y = ln_relu4(a, dinv[n], loff, b, g, be);
    float4 rr = ((const float4*)h1)[(size_t)n * 16 + loff];
    if (lane < 16)
        ((float4*)h2s)[(size_t)p * 16 + loff] =
            make_float4(y.x + rr.x, y.y + rr.y, y.z + rr.z, y.w + rr.w);
}

// ---------------- fused projection + scoring; Wp held in VGPRs ----------------
__global__ __launch_bounds__(256) void k_score(
        const float* __restrict__ h2s, const int* __restrict__ users,
        const int* __restrict__ items, const float* __restrict__ Wp,
        const float* __restrict__ bp, const float* __restrict__ bu,
        const float* __restrict__ bi, const float* __restrict__ mu,
        float* __restrict__ out, int B) {
    int lane = threadIdx.x & 63;
    float wreg[64];                         // column `lane` of Wp
    #pragma unroll
    for (int k = 0; k < 64; ++k) wreg[k] = Wp[k * 64 + lane];
    float bpl = bp[lane];
    int wpb = blockDim.x >> 6;
    int wid = blockIdx.x * wpb + (threadIdx.x >> 6);
    int tw = gridDim.x * wpb;
    for (int p = wid; p < B; p += tw) {
        float hu = h2s[(size_t)p * D + lane];
        float hi = h2s[(size_t)(B + p) * D + lane];
        float pu = bpl, pi = bpl;
        #pragma unroll
        for (int k = 0; k < 64; ++k) {
            float wv = wreg[k];
            pu = fmaf(lane_bcast(hu, k), wv, pu);
            pi = fmaf(lane_bcast(hi, k), wv, pi);
        }
        float t = pu * pi;
        #pragma unroll
        for (int m = 32; m >= 1; m >>= 1) t += __shfl_xor(t, m, 64);
        if (lane == 0) {
            t += bu[users[p]] + bi[items[p]] + mu[0];
            out[p] = fminf(fmaxf(t, 1.0f), 5.0f);
        }
    }
}

extern "C" void kernel_launch(void* const* d_in, const int* in_sizes, int n_in,
                              void* d_out, int out_size, void* d_ws, size_t ws_size,
                              hipStream_t stream) {
    const int*   users = (const int*)d_in[0];
    const int*   items = (const int*)d_in[1];
    const int*   ei2   = (const int*)d_in[2];
    const float* ew    = (const float*)d_in[3];
    const float* U     = (const float*)d_in[4];
    const float* I     = (const float*)d_in[5];
    const float* W0    = (const float*)d_in[6];
    const float* b0    = (const float*)d_in[7];
    const float* g0    = (const float*)d_in[8];
    const float* be0   = (const float*)d_in[9];
    const float* W1    = (const float*)d_in[10];
    const float* b1    = (const float*)d_in[11];
    const float* g1    = (const float*)d_in[12];
    const float* be1   = (const float*)d_in[13];
    const float* Wp    = (const float*)d_in[14];
    const float* bp    = (const float*)d_in[15];
    const float* bu    = (const float*)d_in[16];
    const float* bi    = (const float*)d_in[17];
    const float* mu    = (const float*)d_in[18];

    int B = in_sizes[0];
    int E = in_sizes[2] / 2;
    const int* srcp = ei2;
    const int* dstp = ei2 + E;

    // workspace carve-up (256B aligned); total ~133 MB
    char* p = (char*)d_ws;
    auto alloc = [&](size_t bytes) -> char* {
        char* r = p;
        p += (bytes + 255) & ~(size_t)255;
        return r;
    };
    int*    cbuf    = (int*)  alloc((size_t)(NBINS + 8) * 4);  // bincur|spillcnt|ovfcnt
    int*    bincur  = cbuf;
    int*    spillcnt= cbuf + NBINS;
    int*    ovfcnt  = cbuf + NBINS + 1;
    int*    cursor  = (int*)  alloc((size_t)NN * 4);
    float*  dinv    = (float*)alloc((size_t)NN * 4);
    int4*   ovf     = (int4*) alloc((size_t)OVF_MAX * 16);
    uint2*  spill   = (uint2*)alloc((size_t)SPILL_CAP * 8);      // 2.1 MB
    uint2*  binbuf  = (uint2*)alloc((size_t)NBINS * BINCAP * 8); // 27.4 MB
    uint*   recs    = (uint*) alloc((size_t)NN * CAP * 4);       // 28.2 MB
    ushort* hw2b    = (ushort*)alloc((size_t)NN * D * 2);        // 19.2 MB
    float*  h1      = (float*)alloc((size_t)NN * D * 4);         // 38.4 MB
    float*  h2s     = (float*)alloc((size_t)2 * B * D * 4);      // 16.8 MB
    const uint2* hw2q = (const uint2*)hw2b;

    hipMemsetAsync(cbuf, 0, (size_t)(NBINS + 8) * 4, stream);

    int gW = (NN + 3) / 4;          // one wave per node, 4 waves/block
    int gS = (2 * B + 3) / 4;       // one wave per sample

    // CSR build: bin -> regroup(+spill+deg+dinv)
    k_bin<<<768, 256, 0, stream>>>(srcp, dstp, ew, bincur, binbuf,
                                   spill, spillcnt, E);
    k_regroup<<<NBINS, 256, 0, stream>>>(bincur, binbuf, spill, spillcnt,
                                         recs, cursor, dinv, ovf, ovfcnt);

    // layer 1 (all nodes)
    k_gemm<<<2048, 256, 0, stream>>>(nullptr, U, I, W0, dinv, hw2b);
    k_conv1<<<gW, 256, 0, stream>>>(hw2q, cursor, recs, ovf, ovfcnt, dinv,
                                    b0, g0, be0, U, I, h1);
    // layer 2 (gemm all nodes; conv only sampled nodes)
    k_gemm<<<2048, 256, 0, stream>>>(h1, U, I, W1, dinv, hw2b);
    k_conv2s<<<gS, 256, 0, stream>>>(hw2q, cursor, recs, ovf, ovfcnt, dinv,
                                     b1, g1, be1, users, items, h1, h2s, B);

    // fused projection + scoring
    k_score<<<512, 256, 0, stream>>>(h2s, users, items, Wp, bp, bu, bi, mu,
                                     (float*)d_out, B);
}

// Round 12
// 417.003 us; speedup vs baseline: 1.2160x; 1.0419x over previous
//
#include <hip/hip_runtime.h>

#define NU 100000
#define NI 50000
#define NN 150000   // NU + NI
#define D  64
#define CAP 47      // bucket capacity per dst; E[max in-degree] ~44 for Poisson(21.3)
#define OVF_MAX 4096

// binning params (256-wide bins: regroup block reads exactly its own records)
#define BINSHIFT 8
#define BINW 256                 // dsts per bin
#define NBINS 586                // ceil(150000/256); 586*256 = 150016
#define BINCAP 5848              // per-bin record cap (mean 5461 + 5 sigma), mult of 8
#define STAGE_CAP 12             // LDS stage slots per bin
#define EPT 4                    // edges per thread per batch
#define SPILL_CAP 262144

typedef unsigned int uint;
typedef unsigned short ushort;

// ---------------- helpers ----------------
__device__ __forceinline__ float half_reduce_add(float v) {  // reduce within 32-lane half
    #pragma unroll
    for (int m = 16; m >= 1; m >>= 1) v += __shfl_xor(v, m, 64);
    return v;
}
__device__ __forceinline__ ushort f2bf(float f) {   // round-to-nearest-even
    union { float f; uint i; } c; c.f = f;
    uint r = c.i + 0x7FFF + ((c.i >> 16) & 1);
    return (ushort)(r >> 16);
}
__device__ __forceinline__ float lane_bcast(float v, int l) {
    return __int_as_float(__builtin_amdgcn_readlane(__float_as_int(v), l));
}
// bf14 weight encoding: rounded top-14 bits of f32 (w in [0,1)); decode = 1 AND
__device__ __forceinline__ uint enc14(float w) {
    uint b = __float_as_uint(w) + 0x00020000u;   // round at bit 18
    return b & 0xFFFC0000u;
}
__device__ __forceinline__ float dec14(uint r) {
    return __uint_as_float(r & 0xFFFC0000u);
}
__device__ __forceinline__ void spill_one(int d, uint s, float w,
        uint2* __restrict__ spill, int* __restrict__ spillcnt) {
    int si = atomicAdd(spillcnt, 1);
    if (si < SPILL_CAP) spill[si] = make_uint2(s | enc14(w), (uint)d);
}

// ---------------- pass 1: LDS-staged binning, line-coalesced flushes ----------
// bin record: word0 = src18 | dlocal8<<18 ; word1 = float weight bits
__global__ __launch_bounds__(256) void k_bin(
        const int* __restrict__ src, const int* __restrict__ dst,
        const float* __restrict__ ew, int* __restrict__ bincur,
        uint2* __restrict__ binbuf, uint2* __restrict__ spill,
        int* __restrict__ spillcnt, int E) {
    __shared__ uint2 stage[NBINS][STAGE_CAP];   // ~56 KB -> 2 blocks/CU
    __shared__ int scnt[NBINS];
    int t = threadIdx.x;
    for (int i = t; i < NBINS; i += 256) scnt[i] = 0;
    __syncthreads();
    const int batch = 256 * EPT;
    for (int base = blockIdx.x * batch; base < E; base += gridDim.x * batch) {
        int dd[EPT]; uint ss[EPT]; float ww[EPT]; int ok[EPT];
        #pragma unroll
        for (int k = 0; k < EPT; ++k) {
            int e = base + k * 256 + t;
            ok[k] = (e < E);
            if (ok[k]) { dd[k] = dst[e]; ss[k] = (uint)src[e]; ww[k] = ew[e]; }
        }
        #pragma unroll
        for (int k = 0; k < EPT; ++k) {
            if (!ok[k]) continue;
            int bin = dd[k] >> BINSHIFT;
            int slot = atomicAdd(&scnt[bin], 1);
            if (slot < STAGE_CAP) {
                stage[bin][slot] = make_uint2(
                    ss[k] | ((uint)(dd[k] & (BINW - 1)) << 18),
                    (uint)__float_as_int(ww[k]));
            } else {
                spill_one(dd[k], ss[k], ww[k], spill, spillcnt);  // rare
            }
        }
        __syncthreads();
        for (int bin = t; bin < NBINS; bin += 256) {
            int c = scnt[bin]; if (c > STAGE_CAP) c = STAGE_CAP;
            while (c >= 8) {
                int b0 = atomicAdd(&bincur[bin], 8);
                if (b0 + 8 <= BINCAP) {
                    uint4* o4 = (uint4*)(binbuf + (size_t)bin * BINCAP + b0);
                    uint2* s2 = &stage[bin][c - 8];
                    o4[0] = make_uint4(s2[0].x, s2[0].y, s2[1].x, s2[1].y);
                    o4[1] = make_uint4(s2[2].x, s2[2].y, s2[3].x, s2[3].y);
                    o4[2] = make_uint4(s2[4].x, s2[4].y, s2[5].x, s2[5].y);
                    o4[3] = make_uint4(s2[6].x, s2[6].y, s2[7].x, s2[7].y);
                } else {
                    for (int j = 0; j < 8; ++j) {
                        uint2 r = stage[bin][c - 8 + j];
                        spill_one((bin << BINSHIFT) + (int)(r.x >> 18),
                                  r.x & 0x3FFFFu, __int_as_float((int)r.y),
                                  spill, spillcnt);
                    }
                }
                c -= 8;
            }
            scnt[bin] = c;
        }
        __syncthreads();
    }
    // tail drain: contiguous partial appends (<8 per bin per block)
    for (int bin = t; bin < NBINS; bin += 256) {
        int c = scnt[bin]; if (c > STAGE_CAP) c = STAGE_CAP;
        if (c > 0) {
            int b0 = atomicAdd(&bincur[bin], c);
            for (int j = 0; j < c; ++j) {
                uint2 r = stage[bin][j];
                if (b0 + j < BINCAP) binbuf[(size_t)bin * BINCAP + b0 + j] = r;
                else spill_one((bin << BINSHIFT) + (int)(r.x >> 18),
                               r.x & 0x3FFFFu, __int_as_float((int)r.y),
                               spill, spillcnt);
            }
        }
    }
}

// -------- pass 2: regroup + spills + weighted degree + dinv (one block/bin) ---
__global__ __launch_bounds__(256) void k_regroup(
        const int* __restrict__ bincur, const uint2* __restrict__ binbuf,
        const uint2* __restrict__ spill, const int* __restrict__ spillcnt,
        uint* __restrict__ recs, int* __restrict__ cursor,
        float* __restrict__ dinv, int4* __restrict__ ovf,
        int* __restrict__ ovfcnt) {
    __shared__ uint image[256 * CAP];   // 47 KB, layout == recs layout
    __shared__ int cnt[256];
    __shared__ float ovfw[256];
    int t = threadIdx.x;
    int bin = blockIdx.x;
    cnt[t] = 0; ovfw[t] = 0.0f;
    __syncthreads();
    int dbase = bin << BINSHIFT;
    int nrec = bincur[bin]; if (nrec > BINCAP) nrec = BINCAP;
    const uint2* bb = binbuf + (size_t)bin * BINCAP;
    for (int i = t; i < nrec; i += 256) {
        uint2 r = bb[i];
        int dl = (int)(r.x >> 18);          // 8-bit dlocal, top bits zero
        int slot = atomicAdd(&cnt[dl], 1);
        uint s = r.x & 0x3FFFFu;
        float w = __int_as_float((int)r.y);
        if (slot < CAP) image[dl * CAP + slot] = enc14(w) | s;
        else {                                              // rare high-degree
            atomicAdd(&ovfw[dl], w);
            int o = atomicAdd(ovfcnt, 1);
            if (o < OVF_MAX)
                ovf[o] = make_int4(dbase + dl, (int)s, __float_as_int(w), 0);
        }
    }
    // spill entries (normally ~0); spill words already bf14-encoded
    int ns = spillcnt[0]; if (ns > SPILL_CAP) ns = SPILL_CAP;
    for (int i = t; i < ns; i += 256) {
        uint2 e = spill[i];
        int d = (int)e.y;
        if (d < dbase || d >= dbase + BINW) continue;
        int dl = d - dbase;
        int slot = atomicAdd(&cnt[dl], 1);
        if (slot < CAP) image[dl * CAP + slot] = e.x;
        else {
            float w = dec14(e.x);
            atomicAdd(&ovfw[dl], w);
            int o = atomicAdd(ovfcnt, 1);
            if (o < OVF_MAX) ovf[o] = make_int4(d, (int)(e.x & 0x3FFFFu),
                                                __float_as_int(w), 0);
        }
    }
    __syncthreads();
    int ndl = NN - dbase; if (ndl > 256) ndl = 256;
    if (ndl <= 0) return;
    if (t < ndl) {
        int c = cnt[t];
        cursor[dbase + t] = c;
        if (c > CAP) c = CAP;
        float dg = ovfw[t];
        for (int j = 0; j < c; ++j) dg += dec14(image[t * CAP + j]);
        dinv[dbase + t] = rsqrtf(dg + 1.0f);   // self-loop weight 1 folded in
    }
    int tot = ndl * CAP;
    uint* out = recs + (size_t)dbase * CAP;
    for (int i = t; i < tot; i += 256) out[i] = image[i];  // fully coalesced
}

// ------- small GEMM + dinv row-scale, bf16 out; W held in VGPRs (no LDS) -------
__global__ __launch_bounds__(256) void k_gemm(
        const float* __restrict__ h, const float* __restrict__ U,
        const float* __restrict__ I, const float* __restrict__ W,
        const float* __restrict__ dinv, ushort* __restrict__ out) {
    int lane = threadIdx.x & 63;
    float wreg[64];                         // column `lane` of W, 64 VGPRs
    #pragma unroll
    for (int k = 0; k < 64; ++k) wreg[k] = W[k * 64 + lane];
    int wpb = blockDim.x >> 6;
    int wid = blockIdx.x * wpb + (threadIdx.x >> 6);
    int tw = gridDim.x * wpb;
    for (int n = wid; n < NN; n += tw) {
        float xv;
        if (h) xv = h[(size_t)n * D + lane];
        else   xv = (n < NU) ? U[(size_t)n * D + lane]
                             : I[(size_t)(n - NU) * D + lane];
        float acc = 0.f;
        #pragma unroll
        for (int k = 0; k < 64; ++k)
            acc = fmaf(lane_bcast(xv, k), wreg[k], acc);
        out[(size_t)n * D + lane] = f2bf(acc * dinv[n]);
    }
}

// --- conv accumulate (R9 structure): 2 edges/iter via double readlane,
//     8-edge unrolled chunks => 4 independent gathers in flight, bf14 decode ---
// hw2p = (const uint*)hw2b: row n = 32 dwords, dword p = bf16 feats (2p, 2p+1).
__device__ __forceinline__ float2 conv_accum2(int n, int lane,
        const uint* __restrict__ hw2p, const int* __restrict__ cursor,
        const uint* __restrict__ recs, const int4* __restrict__ ovf,
        const int* __restrict__ ovfcnt) {
    int cnt = __builtin_amdgcn_readfirstlane(cursor[n]);
    if (cnt > CAP) cnt = CAP;
    uint rv = (lane < cnt) ? recs[(size_t)n * CAP + lane] : 0u;
    int odd = lane >> 5;                 // 0: even edges, 1: odd edges
    int laneoff = lane & 31;
    float ax = 0.f, ay = 0.f;
    int cp = (cnt + 7) & ~7;             // pad to chunk of 8 (4 pairs)
    for (int j0 = 0; j0 < cp; j0 += 8) {
        #pragma unroll
        for (int k = 0; k < 4; ++k) {
            uint re = (uint)__builtin_amdgcn_readlane((int)rv, j0 + 2 * k);
            uint ro = (uint)__builtin_amdgcn_readlane((int)rv, j0 + 2 * k + 1);
            uint r  = odd ? ro : re;                         // v_cndmask
            int   s = (int)(r & 0x3FFFFu);
            float w = dec14(r);                              // 1 AND
            uint x = hw2p[(size_t)s * 32 + laneoff];         // 2 bf16 feats
            ax = fmaf(w, __int_as_float((int)(x << 16)), ax);
            ay = fmaf(w, __int_as_float((int)(x & 0xFFFF0000u)), ay);
        }
    }
    // combine even/odd halves
    ax += __shfl_xor(ax, 32, 64);
    ay += __shfl_xor(ay, 32, 64);
    // self-loop term
    uint xs = hw2p[(size_t)n * 32 + laneoff];
    ax += __int_as_float((int)(xs << 16));
    ay += __int_as_float((int)(xs & 0xFFFF0000u));
    // overflow list (normally empty)
    int novf = __builtin_amdgcn_readfirstlane(ovfcnt[0]);
    if (novf > 0) {
        if (novf > OVF_MAX) novf = OVF_MAX;
        for (int j = 0; j < novf; ++j) {
            int4 e = ovf[j];
            if (e.x == n) {
                float w = __int_as_float(e.z);
                uint x = hw2p[(size_t)e.y * 32 + laneoff];
                ax = fmaf(w, __int_as_float((int)(x << 16)), ax);
                ay = fmaf(w, __int_as_float((int)(x & 0xFFFF0000u)), ay);
            }
        }
    }
    return make_float2(ax, ay);
}

// bias + LN + ReLU on pair layout; returns (y0,y1) for feats (2p, 2p+1)
__device__ __forceinline__ float2 ln_relu2(float2 a, float di, int p,
        const float* __restrict__ b, const float* __restrict__ g,
        const float* __restrict__ be) {
    float2 bb = ((const float2*)b)[p];
    float v0 = fmaf(a.x, di, bb.x);
    float v1 = fmaf(a.y, di, bb.y);
    float m = half_reduce_add(v0 + v1) * (1.0f / 64.0f);
    float d0 = v0 - m, d1 = v1 - m;
    float var = half_reduce_add(d0 * d0 + d1 * d1) * (1.0f / 64.0f);
    float rs = rsqrtf(var + 1e-5f);
    float2 gg = ((const float2*)g)[p];
    float2 ee = ((const float2*)be)[p];
    return make_float2(fmaxf(fmaf(d0 * rs, gg.x, ee.x), 0.0f),
                       fmaxf(fmaf(d1 * rs, gg.y, ee.y), 0.0f));
}

// ---------------- layer-1 conv (all nodes) + bias + LN + ReLU + residual ------
__global__ __launch_bounds__(256) void k_conv1(
        const uint* __restrict__ hw2p, const int* __restrict__ cursor,
        const uint* __restrict__ recs, const int4* __restrict__ ovf,
        const int* __restrict__ ovfcnt, const float* __restrict__ dinv,
        const float* __restrict__ b, const float* __restrict__ g,
        const float* __restrict__ be, const float* __restrict__ U,
        const float* __restrict__ I, float* __restrict__ out) {
    int lane = threadIdx.x & 63;
    int n = __builtin_amdgcn_readfirstlane(blockIdx.x * 4 + (threadIdx.x >> 6));
    if (n >= NN) return;
    float2 a = conv_accum2(n, lane, hw2p, cursor, recs, ovf, ovfcnt);
    int p = lane & 31;
    float2 y = ln_relu2(a, dinv[n], p, b, g, be);
    const float* R = (n < NU) ? (U + (size_t)n * D) : (I + (size_t)(n - NU) * D);
    float2 rr = ((const float2*)R)[p];
    if (lane < 32)
        ((float2*)out)[(size_t)n * 32 + p] = make_float2(y.x + rr.x, y.y + rr.y);
}

// ------- FUSED layer-2 conv (sampled) + projection + scoring ------------------
// One wave per sample-pair p: conv both nodes, LN+residual, project with Wp
// (in VGPRs), dot, bias, clip. h2s buffer and a whole dispatch eliminated.
__global__ __launch_bounds__(256) void k_conv2score(
        const uint* __restrict__ hw2p, const int* __restrict__ cursor,
        const uint* __restrict__ recs, const int4* __restrict__ ovf,
        const int* __restrict__ ovfcnt, const float* __restrict__ dinv,
        const float* __restrict__ b, const float* __restrict__ g,
        const float* __restrict__ be, const int* __restrict__ users,
        const int* __restrict__ items, const float* __restrict__ h1,
        const float* __restrict__ Wp, const float* __restrict__ bp,
        const float* __restrict__ bu, const float* __restrict__ bi,
        const float* __restrict__ mu, float* __restrict__ out, int B) {
    int lane = threadIdx.x & 63;
    float wreg[64];                         // column `lane` of Wp
    #pragma unroll
    for (int k = 0; k < 64; ++k) wreg[k] = Wp[k * 64 + lane];
    float bpl = bp[lane];
    int q = lane & 31;
    int wpb = blockDim.x >> 6;
    int wid = blockIdx.x * wpb + (threadIdx.x >> 6);
    int tw = gridDim.x * wpb;
    for (int p = wid; p < B; p += tw) {
        int un = users[p];
        int in = NU + items[p];
        // --- user node conv + LN + residual (pair layout, valid in all lanes)
        int nu = __builtin_amdgcn_readfirstlane(un);
        float2 au = conv_accum2(nu, lane, hw2p, cursor, recs, ovf, ovfcnt);
        float2 yu = ln_relu2(au, dinv[nu], q, b, g, be);
        float2 ru = ((const float2*)h1)[(size_t)nu * 32 + q];
        float2 hu = make_float2(yu.x + ru.x, yu.y + ru.y);
        // --- item node
        int ni = __builtin_amdgcn_readfirstlane(in);
        float2 ai = conv_accum2(ni, lane, hw2p, cursor, recs, ovf, ovfcnt);
        float2 yi = ln_relu2(ai, dinv[ni], q, b, g, be);
        float2 ri = ((const float2*)h1)[(size_t)ni * 32 + q];
        float2 hi = make_float2(yi.x + ri.x, yi.y + ri.y);
        // --- projection (feat 2j from .x, 2j+1 from .y) + dot
        float pu = bpl, pi = bpl;
        #pragma unroll
        for (int j = 0; j < 32; ++j) {
            pu = fmaf(lane_bcast(hu.x, j), wreg[2 * j], pu);
            pu = fmaf(lane_bcast(hu.y, j), wreg[2 * j + 1], pu);
            pi = fmaf(lane_bcast(hi.x, j), wreg[2 * j], pi);
            pi = fmaf(lane_bcast(hi.y, j), wreg[2 * j + 1], pi);
        }
        float t = pu * pi;
        #pragma unroll
        for (int m = 32; m >= 1; m >>= 1) t += __shfl_xor(t, m, 64);
        if (lane == 0) {
            t += bu[un] + bi[in - NU] + mu[0];
            out[p] = fminf(fmaxf(t, 1.0f), 5.0f);
        }
    }
}

extern "C" void kernel_launch(void* const* d_in, const int* in_sizes, int n_in,
                              void* d_out, int out_size, void* d_ws, size_t ws_size,
                              hipStream_t stream) {
    const int*   users = (const int*)d_in[0];
    const int*   items = (const int*)d_in[1];
    const int*   ei2   = (const int*)d_in[2];
    const float* ew    = (const float*)d_in[3];
    const float* U     = (const float*)d_in[4];
    const float* I     = (const float*)d_in[5];
    const float* W0    = (const float*)d_in[6];
    const float* b0    = (const float*)d_in[7];
    const float* g0    = (const float*)d_in[8];
    const float* be0   = (const float*)d_in[9];
    const float* W1    = (const float*)d_in[10];
    const float* b1    = (const float*)d_in[11];
    const float* g1    = (const float*)d_in[12];
    const float* be1   = (const float*)d_in[13];
    const float* Wp    = (const float*)d_in[14];
    const float* bp    = (const float*)d_in[15];
    const float* bu    = (const float*)d_in[16];
    const float* bi    = (const float*)d_in[17];
    const float* mu    = (const float*)d_in[18];

    int B = in_sizes[0];
    int E = in_sizes[2] / 2;
    const int* srcp = ei2;
    const int* dstp = ei2 + E;

    // workspace carve-up (256B aligned); total ~116 MB
    char* p = (char*)d_ws;
    auto alloc = [&](size_t bytes) -> char* {
        char* r = p;
        p += (bytes + 255) & ~(size_t)255;
        return r;
    };
    int*    cbuf    = (int*)  alloc((size_t)(NBINS + 8) * 4);  // bincur|spillcnt|ovfcnt
    int*    bincur  = cbuf;
    int*    spillcnt= cbuf + NBINS;
    int*    ovfcnt  = cbuf + NBINS + 1;
    int*    cursor  = (int*)  alloc((size_t)NN * 4);
    float*  dinv    = (float*)alloc((size_t)NN * 4);
    int4*   ovf     = (int4*) alloc((size_t)OVF_MAX * 16);
    uint2*  spill   = (uint2*)alloc((size_t)SPILL_CAP * 8);      // 2.1 MB
    uint2*  binbuf  = (uint2*)alloc((size_t)NBINS * BINCAP * 8); // 27.4 MB
    uint*   recs    = (uint*) alloc((size_t)NN * CAP * 4);       // 28.2 MB
    ushort* hw2b    = (ushort*)alloc((size_t)NN * D * 2);        // 19.2 MB
    float*  h1      = (float*)alloc((size_t)NN * D * 4);         // 38.4 MB
    const uint* hw2p = (const uint*)hw2b;

    hipMemsetAsync(cbuf, 0, (size_t)(NBINS + 8) * 4, stream);

    int gW = (NN + 3) / 4;          // one wave per node, 4 waves/block

    // CSR build: bin -> regroup(+spill+deg+dinv)
    k_bin<<<768, 256, 0, stream>>>(srcp, dstp, ew, bincur, binbuf,
                                   spill, spillcnt, E);
    k_regroup<<<NBINS, 256, 0, stream>>>(bincur, binbuf, spill, spillcnt,
                                         recs, cursor, dinv, ovf, ovfcnt);

    // layer 1 (all nodes)
    k_gemm<<<2048, 256, 0, stream>>>(nullptr, U, I, W0, dinv, hw2b);
    k_conv1<<<gW, 256, 0, stream>>>(hw2p, cursor, recs, ovf, ovfcnt, dinv,
                                    b0, g0, be0, U, I, h1);
    // layer 2: gemm all nodes, then fused sampled-conv + projection + scoring
    k_gemm<<<2048, 256, 0, stream>>>(h1, U, I, W1, dinv, hw2b);
    k_conv2score<<<1024, 256, 0, stream>>>(hw2p, cursor, recs, ovf, ovfcnt, dinv,
                                           b1, g1, be1, users, items, h1,
                                           Wp, bp, bu, bi, mu,
                                           (float*)d_out, B);
}